// Round 3
// baseline (644.019 us; speedup 1.0000x reference)
//
#include <hip/hip_runtime.h>
#include <hip/hip_bf16.h>

typedef __attribute__((ext_vector_type(8))) short bf16x8;
typedef __attribute__((ext_vector_type(4))) float f32x4;

__device__ __forceinline__ short f2bf_bits(float f) {
    __hip_bfloat16 h = __float2bfloat16(f);
    short s;
    __builtin_memcpy(&s, &h, 2);
    return s;
}

__device__ __forceinline__ float bf_bits2f(short s) {
    unsigned int u = ((unsigned int)(unsigned short)s) << 16;
    float f;
    __builtin_memcpy(&f, &u, 4);
    return f;
}

__device__ __forceinline__ bf16x8 load8(const float* p) {
    float4 a = *(const float4*)p;
    float4 b = *(const float4*)(p + 4);
    bf16x8 r;
    r[0] = f2bf_bits(a.x); r[1] = f2bf_bits(a.y);
    r[2] = f2bf_bits(a.z); r[3] = f2bf_bits(a.w);
    r[4] = f2bf_bits(b.x); r[5] = f2bf_bits(b.y);
    r[6] = f2bf_bits(b.z); r[7] = f2bf_bits(b.w);
    return r;
}
__device__ __forceinline__ bf16x8 load8(const __hip_bfloat16* p) {
    return *(const bf16x8*)p;
}

__device__ __forceinline__ void store_out(__hip_bfloat16* p, float v) {
    *p = __float2bfloat16(v);
}
__device__ __forceinline__ void store_out(float* p, float v) { *p = v; }

// ---------------------------------------------------------------------------
// merged f32 -> bf16 bulk convert of three buffers (8 elems/thread)
// ---------------------------------------------------------------------------
__global__ void cvt3_f32_bf16(const float* __restrict__ a, short* __restrict__ da, int na8,
                              const float* __restrict__ b, short* __restrict__ db, int nb8,
                              const float* __restrict__ c, short* __restrict__ dc, int nc8) {
    int i = blockIdx.x * 256 + threadIdx.x;
    if (i < na8) {
        *(bf16x8*)(da + (size_t)i * 8) = load8(a + (size_t)i * 8);
    } else if ((i -= na8) < nb8) {
        *(bf16x8*)(db + (size_t)i * 8) = load8(b + (size_t)i * 8);
    } else if ((i -= nb8) < nc8) {
        *(bf16x8*)(dc + (size_t)i * 8) = load8(c + (size_t)i * 8);
    }
}

// ---------------------------------------------------------------------------
// 256x256 8-phase GEMM (bf16 x bf16): C = A(MxK) * B(NxK)^T + bias.
// T2 st_16x32 LDS swizzle + T3/T4 counted-vmcnt 8-phase pipeline + T5 setprio.
// 512 threads = 8 waves (2M x 4N), per-wave 128x64 output, BK=64, 128 KiB LDS.
// ---------------------------------------------------------------------------
#define GB_REG 65536

__device__ __forceinline__ int half_off(int buf, int half) {
    return buf * 32768 + half * 16384;
}

template <typename TC>
__global__ __launch_bounds__(512) void gemm256(
    const __hip_bfloat16* __restrict__ A, const __hip_bfloat16* __restrict__ B,
    const float* __restrict__ bias, TC* __restrict__ C, int M, int N, int K)
{
    __shared__ char smem[131072];

    const int tid  = threadIdx.x;
    const int lane = tid & 63;
    const int wid  = tid >> 6;
    const int quad = lane >> 4;
    const int m16  = lane & 15;
    const int wmg  = wid >> 2;       // 0..1 -> A half (M 128-row group)
    const int wng  = wid & 3;        // 0..3 -> N 64-col group
    const int bhalf = wng >> 1;      // B half
    const int bsub  = (wng & 1) * 4; // subtile row base within B half

    // XCD-chunked block swizzle (bijective: nwg % 8 == 0 for our shapes)
    const int gx  = gridDim.x;
    const int nwg = gx * gridDim.y;
    int lin = blockIdx.y * gx + blockIdx.x;
    if ((nwg & 7) == 0) {
        int q = nwg >> 3;
        lin = (lin & 7) * q + (lin >> 3);
    }
    const int bn = lin % gx, bm = lin / gx;
    const int mBase = bm * 256, nBase = bn * 256;

    // swizzled ds_read offset within a subtile
    const int roff = (m16 << 6) | ((quad * 16) ^ ((m16 & 8) << 2));

    // staging: thread's linear LDS slot X = l*8192 + tid*16 -> source (r,c)
    int r_s[2], c_s[2];
    #pragma unroll
    for (int l = 0; l < 2; ++l) {
        int sub = l * 8 + wid;
        int r16 = (tid >> 2) & 15;
        int cb  = ((tid & 3) * 16) ^ ((r16 & 8) << 2);
        r_s[l] = (sub >> 1) * 16 + r16;
        c_s[l] = (sub & 1) * 32 + (cb >> 1);
    }

    const __hip_bfloat16* Ab = A + (size_t)mBase * K;
    const __hip_bfloat16* Bb = B + (size_t)nBase * K;

    auto stage = [&](int region, const __hip_bfloat16* base, int buf, int half, int tile) {
        const __hip_bfloat16* gb = base + (size_t)(half * 128) * K + tile * 64;
        #pragma unroll
        for (int l = 0; l < 2; ++l) {
            const __hip_bfloat16* g = gb + (size_t)r_s[l] * K + c_s[l];
            short* lb = (short*)(smem + region + half_off(buf, half) + l * 8192 + wid * 1024);
            __builtin_amdgcn_global_load_lds(
                (__attribute__((address_space(1))) void*)g,
                (__attribute__((address_space(3))) void*)lb, 16, 0, 0);
        }
    };

    f32x4 acc[8][4] = {};
    bf16x8 afr[4][2];       // 4 m-frags x 2 k-slices (current m-quartet)
    bf16x8 bfr[2][2][2];    // [n-pair g][j][ks] -- both n-pairs stay live

    auto LD_A = [&](int buf, int g) {
        const char* base = smem + half_off(buf, wmg) + (g ? 8192 : 0);
        #pragma unroll
        for (int m = 0; m < 4; ++m)
            #pragma unroll
            for (int ks = 0; ks < 2; ++ks)
                afr[m][ks] = *(const bf16x8*)(base + ((m * 2 + ks) << 10) + roff);
    };
    auto LD_B = [&](int buf, int g) {
        const char* base = smem + GB_REG + half_off(buf, bhalf) + ((bsub + g * 2) << 11);
        #pragma unroll
        for (int j = 0; j < 2; ++j)
            #pragma unroll
            for (int ks = 0; ks < 2; ++ks)
                bfr[g][j][ks] = *(const bf16x8*)(base + ((j * 2 + ks) << 10) + roff);
    };
    auto MM = [&](int mo, int g) {
        #pragma unroll
        for (int m = 0; m < 4; ++m)
            #pragma unroll
            for (int j = 0; j < 2; ++j)
                #pragma unroll
                for (int ks = 0; ks < 2; ++ks)
                    acc[mo + m][g * 2 + j] = __builtin_amdgcn_mfma_f32_16x16x32_bf16(
                        afr[m][ks], bfr[g][j][ks], acc[mo + m][g * 2 + j], 0, 0, 0);
    };

#define SBAR() __builtin_amdgcn_s_barrier()
#define WAIT_LGKM0() do { asm volatile("s_waitcnt lgkmcnt(0)" ::: "memory"); \
                          __builtin_amdgcn_sched_barrier(0); } while (0)
#define WAIT_VM4()   do { asm volatile("s_waitcnt vmcnt(4)"   ::: "memory"); \
                          __builtin_amdgcn_sched_barrier(0); } while (0)

    const int NT = K >> 6;

    // prologue: tile0 -> buf0 (all 4 halves), tile1 -> buf1 (B.h0, A.h0)
    stage(GB_REG, Bb, 0, 0, 0);
    stage(0,      Ab, 0, 0, 0);
    stage(GB_REG, Bb, 0, 1, 0);
    stage(0,      Ab, 0, 1, 0);
    stage(GB_REG, Bb, 1, 0, 1);
    stage(0,      Ab, 1, 0, 1);
    WAIT_VM4();      // tile0's 8 loads done; tile1's 4 may fly
    SBAR();

    for (int i = 0; i < (NT >> 1); ++i) {
        const int to = 2 * i + 1;
        const int t2 = min(2 * i + 2, NT - 1);
        const int t3 = min(2 * i + 3, NT - 1);
        // P0: quadrant (m0-3, n0-1) of even tile (buf0)
        LD_A(0, 0); LD_B(0, 0);
        stage(GB_REG, Bb, 1, 1, to);
        SBAR(); WAIT_LGKM0();
        __builtin_amdgcn_s_setprio(1); MM(0, 0); __builtin_amdgcn_s_setprio(0);
        SBAR();
        // P1: (m0-3, n2-3)
        LD_B(0, 1);
        stage(0, Ab, 1, 1, to);
        SBAR(); WAIT_LGKM0();
        __builtin_amdgcn_s_setprio(1); MM(0, 1); __builtin_amdgcn_s_setprio(0);
        SBAR();
        // P2: (m4-7, n2-3)
        LD_A(0, 1);
        stage(GB_REG, Bb, 0, 0, t2);
        SBAR(); WAIT_LGKM0();
        __builtin_amdgcn_s_setprio(1); MM(4, 1); __builtin_amdgcn_s_setprio(0);
        SBAR();
        // P3: (m4-7, n0-1) register-only; gate odd-tile arrival (counted vmcnt)
        stage(0, Ab, 0, 0, t2);
        WAIT_VM4();
        SBAR();
        __builtin_amdgcn_s_setprio(1); MM(4, 0); __builtin_amdgcn_s_setprio(0);
        SBAR();
        // P4: odd tile (buf1), (m0-3, n0-1)
        LD_A(1, 0); LD_B(1, 0);
        stage(GB_REG, Bb, 0, 1, t2);
        SBAR(); WAIT_LGKM0();
        __builtin_amdgcn_s_setprio(1); MM(0, 0); __builtin_amdgcn_s_setprio(0);
        SBAR();
        // P5: (m0-3, n2-3)
        LD_B(1, 1);
        stage(0, Ab, 0, 1, t2);
        SBAR(); WAIT_LGKM0();
        __builtin_amdgcn_s_setprio(1); MM(0, 1); __builtin_amdgcn_s_setprio(0);
        SBAR();
        // P6: (m4-7, n2-3)
        LD_A(1, 1);
        stage(GB_REG, Bb, 1, 0, t3);
        SBAR(); WAIT_LGKM0();
        __builtin_amdgcn_s_setprio(1); MM(4, 1); __builtin_amdgcn_s_setprio(0);
        SBAR();
        // P7: (m4-7, n0-1) register-only; gate even-tile arrival
        stage(0, Ab, 1, 0, t3);
        WAIT_VM4();
        SBAR();
        __builtin_amdgcn_s_setprio(1); MM(4, 0); __builtin_amdgcn_s_setprio(0);
        SBAR();
    }

#undef SBAR
#undef WAIT_LGKM0
#undef WAIT_VM4

    float bv[4];
    #pragma unroll
    for (int j = 0; j < 4; ++j)
        bv[j] = bias[nBase + wng * 64 + j * 16 + m16];

    #pragma unroll
    for (int mf = 0; mf < 8; ++mf) {
        #pragma unroll
        for (int j = 0; j < 4; ++j) {
            const int col = nBase + wng * 64 + j * 16 + m16;
            #pragma unroll
            for (int r = 0; r < 4; ++r) {
                const int row = mBase + wmg * 128 + mf * 16 + quad * 4 + r;
                store_out(&C[(size_t)row * N + col], acc[mf][j][r] + bv[j]);
            }
        }
    }
}

// ---------------------------------------------------------------------------
// Fallback GEMM (fp32 inputs converted inline) — safety net if ws too small
// ---------------------------------------------------------------------------
#define LDSS 40

template <typename TA, typename TB, typename TC>
__global__ __launch_bounds__(256) void gemm_bt_bias(
    const TA* __restrict__ A, const TB* __restrict__ B,
    const float* __restrict__ bias, TC* __restrict__ C, int M, int N, int K)
{
    __shared__ short As[128 * LDSS];
    __shared__ short Bs[128 * LDSS];

    const int tid  = threadIdx.x;
    const int lane = tid & 63;
    const int wid  = tid >> 6;
    const int quad = lane >> 4;
    const int m16  = lane & 15;

    const int mBase = blockIdx.y * 128;
    const int nBase = blockIdx.x * 128;
    const int wm = (wid >> 1) * 64;
    const int wn = (wid & 1) * 64;

    f32x4 acc[4][4] = {};
    const int srow = tid >> 2;
    const int sgrp = (tid & 3) * 8;

    for (int kt = 0; kt < K; kt += 32) {
        __syncthreads();
        for (int p = 0; p < 2; ++p) {
            int r = srow + p * 64;
            *(bf16x8*)(&As[r * LDSS + sgrp]) =
                load8(A + (size_t)(mBase + r) * K + kt + sgrp);
            *(bf16x8*)(&Bs[r * LDSS + sgrp]) =
                load8(B + (size_t)(nBase + r) * K + kt + sgrp);
        }
        __syncthreads();

        bf16x8 afr[4], bfr[4];
        #pragma unroll
        for (int i = 0; i < 4; ++i)
            afr[i] = *(const bf16x8*)(&As[(wm + 16 * i + m16) * LDSS + quad * 8]);
        #pragma unroll
        for (int j = 0; j < 4; ++j)
            bfr[j] = *(const bf16x8*)(&Bs[(wn + 16 * j + m16) * LDSS + quad * 8]);
        #pragma unroll
        for (int i = 0; i < 4; ++i)
            #pragma unroll
            for (int j = 0; j < 4; ++j)
                acc[i][j] = __builtin_amdgcn_mfma_f32_16x16x32_bf16(
                    afr[i], bfr[j], acc[i][j], 0, 0, 0);
    }

    float bv[4];
    #pragma unroll
    for (int j = 0; j < 4; ++j)
        bv[j] = bias[nBase + wn + 16 * j + m16];

    #pragma unroll
    for (int i = 0; i < 4; ++i)
        #pragma unroll
        for (int j = 0; j < 4; ++j) {
            int col = nBase + wn + 16 * j + m16;
            #pragma unroll
            for (int r = 0; r < 4; ++r) {
                int row = mBase + wm + 16 * i + quad * 4 + r;
                store_out(&C[(size_t)row * N + col], acc[i][j][r] + bv[j]);
            }
        }
}

// ---------------------------------------------------------------------------
// RoPE in-place on q (heads 0..23) and k (cols 3072..3327), 8 elems/thread
// ---------------------------------------------------------------------------
__global__ void rope_kernel(__hip_bfloat16* __restrict__ qkv,
                            const float* __restrict__ cosb,
                            const float* __restrict__ sinb, int T)
{
    int idx = blockIdx.x * 256 + threadIdx.x;          // (t, h, j): j = d/8
    int total = T * 26 * 8;
    if (idx >= total) return;
    int j = idx & 7;
    int h = (idx >> 3) % 26;
    int t = idx / (26 * 8);
    int col = (h < 24) ? h * 128 : 3072 + (h - 24) * 128;
    int d0 = j * 8;
    size_t base = (size_t)t * 3584 + col + d0;
    bf16x8 x1 = *(const bf16x8*)((const short*)qkv + base);
    bf16x8 x2 = *(const bf16x8*)((const short*)qkv + base + 64);
    float4 c0 = *(const float4*)(cosb + t * 64 + d0);
    float4 c1 = *(const float4*)(cosb + t * 64 + d0 + 4);
    float4 s0 = *(const float4*)(sinb + t * 64 + d0);
    float4 s1 = *(const float4*)(sinb + t * 64 + d0 + 4);
    float cc[8] = {c0.x, c0.y, c0.z, c0.w, c1.x, c1.y, c1.z, c1.w};
    float ss[8] = {s0.x, s0.y, s0.z, s0.w, s1.x, s1.y, s1.z, s1.w};
    bf16x8 o1, o2;
    #pragma unroll
    for (int i = 0; i < 8; ++i) {
        float f1 = bf_bits2f(x1[i]);
        float f2 = bf_bits2f(x2[i]);
        o1[i] = f2bf_bits(f1 * cc[i] - f2 * ss[i]);
        o2[i] = f2bf_bits(f2 * cc[i] + f1 * ss[i]);
    }
    *(bf16x8*)((short*)qkv + base)      = o1;
    *(bf16x8*)((short*)qkv + base + 64) = o2;
}

// ---------------------------------------------------------------------------
// Flash attention v5: TLP-first. QBLK=64 (16 q per wave), single-buffered V^T,
// small LDS + small register footprint -> 4-6 blocks/CU. Raw barriers (global
// V loads stay in flight across B1), LPT heavy-first remap, setprio on MFMA.
// ---------------------------------------------------------------------------
#define SM_SHIFT 12.0f

__global__ __launch_bounds__(256, 4) void attn_kernel(
    const __hip_bfloat16* __restrict__ qkv,  // T x 3584 (rope applied)
    __hip_bfloat16* __restrict__ out,        // T x 3072
    const int* __restrict__ seq_len_p, const int* __restrict__ window_p)
{
    const int S = seq_len_p[0];
    const int window = window_p[0];
    const float scale = 0.088388347648318447f;  // 1/sqrt(128)

    const int h   = blockIdx.y;
    const int kvh = h / 12;
    const int tid  = threadIdx.x;
    const int lane = tid & 63;
    const int wid  = tid >> 6;
    const int quad = lane >> 4;
    const int m16  = lane & 15;

    // heavy-first remap: descending qb within each batch (LPT scheduling)
    const int nbb = S >> 6;                  // q-blocks (64 rows) per batch
    const int b   = blockIdx.x / nbb;
    const int ib  = blockIdx.x - b * nbb;
    const int qb  = (nbb - 1 - ib) << 6;
    const int qb_global = b * S + qb;

    __shared__ short Vt[128 * 72];      // V^T: V[key][d] at [d*72 + key + ((d>>3)&1)*32]
    __shared__ short Ps[4][16 * 40];    // per-wave P [q(16)][key(32)], stride 40

    const size_t kvrow0 = (size_t)(b * S) * 3584 + 3072 + kvh * 128;

    // Q fragments: wave wid handles q rows [qb + wid*16, +16)
    bf16x8 qf[4];
    {
        const __hip_bfloat16* qp =
            qkv + (size_t)(qb_global + wid * 16 + m16) * 3584 + h * 128;
        #pragma unroll
        for (int dc = 0; dc < 4; ++dc)
            qf[dc] = *(const bf16x8*)(qp + dc * 32 + quad * 8);
    }

    f32x4 accO[8] = {};
    float lq = 0.f;

    int ka0 = qb - window + 1;
    if (ka0 < 0) ka0 = 0;
    ka0 &= ~31;
    const int kend = qb + 64;
    const int niter = (kend - ka0) >> 5;

    // staging geometry (per thread): 2 chunks, each = one V row-slice of 8
    const int skey = tid & 31;          // key within 32-tile
    const int sgg0 = tid >> 5;          // 0..7  (chunk 0 d-group)
    const int sgg1 = sgg0 + 8;          // 8..15 (chunk 1 d-group)

    for (int it = 0; it < niter; ++it) {
        const int kt = ka0 + it * 32;

        // issue V loads for this tile (fly across B1)
        bf16x8 v0 = *(const bf16x8*)(qkv + kvrow0 + (size_t)(kt + skey) * 3584 + 256 + sgg0 * 8);
        bf16x8 v1 = *(const bf16x8*)(qkv + kvrow0 + (size_t)(kt + skey) * 3584 + 256 + sgg1 * 8);

        // B1: previous iteration's PV readers are done (their ds_reads were
        // consumed by MFMA before reaching this barrier)
        __builtin_amdgcn_s_barrier();

        // transpose-write V^T (compiler inserts vmcnt wait for v0/v1)
        {
            short* dst0 = &Vt[(sgg0 * 8) * 72 + skey + (sgg0 & 1) * 32];
            short* dst1 = &Vt[(sgg1 * 8) * 72 + skey + (sgg1 & 1) * 32];
            #pragma unroll
            for (int i2 = 0; i2 < 8; ++i2) dst0[i2 * 72] = v0[i2];
            #pragma unroll
            for (int i2 = 0; i2 < 8; ++i2) dst1[i2 * 72] = v1[i2];
        }
        asm volatile("s_waitcnt lgkmcnt(0)" ::: "memory");
        // B2: Vt ready for all waves
        __builtin_amdgcn_s_barrier();
        __builtin_amdgcn_sched_barrier(0);

        // S^T = K * Q^T (K frags direct from global, L2-hot)
        f32x4 sacc[2] = {};   // [st]
        #pragma unroll
        for (int st = 0; st < 2; ++st) {
            const __hip_bfloat16* kp =
                qkv + kvrow0 + (size_t)(kt + st * 16 + m16) * 3584;
            #pragma unroll
            for (int dc = 0; dc < 4; ++dc) {
                bf16x8 kf = *(const bf16x8*)(kp + dc * 32 + quad * 8);
                sacc[st] = __builtin_amdgcn_mfma_f32_16x16x32_bf16(
                    kf, qf[dc], sacc[st], 0, 0, 0);
            }
        }

        // fixed-shift softmax: p = exp(s*scale - SHIFT); no rescaling ever.
        // S^T C-layout: col m16 = q, row quad*4 + r + st*16 = key
        {
            const int qmin = qb + wid * 16;               // wave-uniform
            short* prow = &Ps[wid][m16 * 40];
            float psum = 0.f;
            if (kt <= qmin - 31 && kt >= qmin + 16 - window) {
                // interior: all 32 keys valid for all 16 q
                #pragma unroll
                for (int st = 0; st < 2; ++st)
                    #pragma unroll
                    for (int r = 0; r < 4; ++r) {
                        float pp = __expf(fminf(
                            sacc[st][r] * scale - SM_SHIFT, 80.f));
                        psum += pp;
                        prow[st * 16 + quad * 4 + r] = f2bf_bits(pp);
                    }
            } else {
                const int dl_base = (qmin + m16) - (kt + quad * 4);
                #pragma unroll
                for (int st = 0; st < 2; ++st)
                    #pragma unroll
                    for (int r = 0; r < 4; ++r) {
                        int dl = dl_base - st * 16 - r;
                        float pp = ((unsigned)dl < (unsigned)window)
                            ? __expf(fminf(sacc[st][r] * scale - SM_SHIFT, 80.f))
                            : 0.f;
                        psum += pp;
                        prow[st * 16 + quad * 4 + r] = f2bf_bits(pp);
                    }
            }
            psum += __shfl_xor(psum, 16, 64);
            psum += __shfl_xor(psum, 32, 64);
            lq += psum;
        }

        // PV: A = P (wave-private LDS), B = V^T frag
        {
            bf16x8 pf = *(const bf16x8*)(&Ps[wid][m16 * 40 + quad * 8]);
            __builtin_amdgcn_s_setprio(1);
            #pragma unroll
            for (int dt = 0; dt < 8; ++dt) {
                int row = dt * 16 + m16;
                bf16x8 vf = *(const bf16x8*)(&Vt[row * 72 + quad * 8 + ((row >> 3) & 1) * 32]);
                accO[dt] = __builtin_amdgcn_mfma_f32_16x16x32_bf16(pf, vf, accO[dt], 0, 0, 0);
            }
            __builtin_amdgcn_s_setprio(0);
        }
    }

    // epilogue: O /= l
    {
        float li[4];
        #pragma unroll
        for (int r = 0; r < 4; ++r)
            li[r] = 1.0f / __shfl(lq, quad * 4 + r, 64);
        #pragma unroll
        for (int r = 0; r < 4; ++r) {
            int t = qb_global + wid * 16 + quad * 4 + r;
            __hip_bfloat16* op = out + (size_t)t * 3072 + h * 128 + m16;
            #pragma unroll
            for (int dt = 0; dt < 8; ++dt)
                op[dt * 16] = __float2bfloat16(accO[dt][r] * li[r]);
        }
    }
}

// ---------------------------------------------------------------------------
extern "C" void kernel_launch(void* const* d_in, const int* in_sizes, int n_in,
                              void* d_out, int out_size, void* d_ws, size_t ws_size,
                              hipStream_t stream) {
    const float* hidden = (const float*)d_in[0];
    const float* w_qkv  = (const float*)d_in[1];
    const float* b_qkv  = (const float*)d_in[2];
    const float* w_o    = (const float*)d_in[3];
    const float* b_o    = (const float*)d_in[4];
    const float* cosb   = (const float*)d_in[5];
    const float* sinb   = (const float*)d_in[6];
    const int* seq_len_p = (const int*)d_in[7];
    const int* window_p  = (const int*)d_in[8];

    const int HID  = in_sizes[4];            // 3072
    const int NQKV = in_sizes[2];            // 3584
    const int T    = in_sizes[0] / HID;      // 4096

    size_t off = 0;
    auto alloc = [&](size_t bytes) {
        char* p = (char*)d_ws + off;
        off = (off + bytes + 255) & ~(size_t)255;
        return p;
    };
    __hip_bfloat16* qkv      = (__hip_bfloat16*)alloc((size_t)T * NQKV * 2);
    __hip_bfloat16* attn_out = (__hip_bfloat16*)alloc((size_t)T * HID * 2);
    __hip_bfloat16* hid_bf = (__hip_bfloat16*)alloc((size_t)T * HID * 2);
    __hip_bfloat16* wq_bf  = (__hip_bfloat16*)alloc((size_t)NQKV * HID * 2);
    __hip_bfloat16* wo_bf  = (__hip_bfloat16*)alloc((size_t)HID * HID * 2);
    const bool pre = (ws_size >= off);
    const bool big = pre && (T % 256 == 0) && (NQKV % 256 == 0) &&
                     (HID % 256 == 0) && (HID % 64 == 0);

    dim3 blk(256);

    if (big) {
        int n8h = T * HID / 8, n8q = NQKV * HID / 8, n8o = HID * HID / 8;
        int n8 = n8h + n8q + n8o;
        cvt3_f32_bf16<<<dim3((n8 + 255) / 256), blk, 0, stream>>>(
            hidden, (short*)hid_bf, n8h, w_qkv, (short*)wq_bf, n8q,
            w_o, (short*)wo_bf, n8o);
        gemm256<__hip_bfloat16><<<dim3(NQKV / 256, T / 256), dim3(512), 0, stream>>>(
            hid_bf, wq_bf, b_qkv, qkv, T, NQKV, HID);
    } else {
        gemm_bt_bias<float, float, __hip_bfloat16>
            <<<dim3(NQKV / 128, T / 128), blk, 0, stream>>>(
            hidden, w_qkv, b_qkv, qkv, T, NQKV, HID);
    }

    int total = T * 26 * 8;
    rope_kernel<<<dim3((total + 255) / 256), blk, 0, stream>>>(qkv, cosb, sinb, T);

    attn_kernel<<<dim3(T / 64, 24), blk, 0, stream>>>(qkv, attn_out, seq_len_p, window_p);

    if (big) {
        gemm256<float><<<dim3(HID / 256, T / 256), dim3(512), 0, stream>>>(
            attn_out, wo_bf, b_o, (float*)d_out, T, HID, HID);
    } else {
        gemm_bt_bias<__hip_bfloat16, float, float>
            <<<dim3(HID / 128, T / 128), blk, 0, stream>>>(
            attn_out, w_o, b_o, (float*)d_out, T, HID, HID);
    }
}

// Round 4
// 480.725 us; speedup vs baseline: 1.3397x; 1.3397x over previous
//
#include <hip/hip_runtime.h>
#include <hip/hip_bf16.h>

typedef __attribute__((ext_vector_type(8))) short bf16x8;
typedef __attribute__((ext_vector_type(4))) float f32x4;

__device__ __forceinline__ short f2bf_bits(float f) {
    __hip_bfloat16 h = __float2bfloat16(f);
    short s;
    __builtin_memcpy(&s, &h, 2);
    return s;
}

__device__ __forceinline__ float bf_bits2f(short s) {
    unsigned int u = ((unsigned int)(unsigned short)s) << 16;
    float f;
    __builtin_memcpy(&f, &u, 4);
    return f;
}

__device__ __forceinline__ bf16x8 load8(const float* p) {
    float4 a = *(const float4*)p;
    float4 b = *(const float4*)(p + 4);
    bf16x8 r;
    r[0] = f2bf_bits(a.x); r[1] = f2bf_bits(a.y);
    r[2] = f2bf_bits(a.z); r[3] = f2bf_bits(a.w);
    r[4] = f2bf_bits(b.x); r[5] = f2bf_bits(b.y);
    r[6] = f2bf_bits(b.z); r[7] = f2bf_bits(b.w);
    return r;
}
__device__ __forceinline__ bf16x8 load8(const __hip_bfloat16* p) {
    return *(const bf16x8*)p;
}

__device__ __forceinline__ void store_out(__hip_bfloat16* p, float v) {
    *p = __float2bfloat16(v);
}
__device__ __forceinline__ void store_out(float* p, float v) { *p = v; }

// ---------------------------------------------------------------------------
// merged f32 -> bf16 bulk convert of three buffers (8 elems/thread)
// ---------------------------------------------------------------------------
__global__ void cvt3_f32_bf16(const float* __restrict__ a, short* __restrict__ da, int na8,
                              const float* __restrict__ b, short* __restrict__ db, int nb8,
                              const float* __restrict__ c, short* __restrict__ dc, int nc8) {
    int i = blockIdx.x * 256 + threadIdx.x;
    if (i < na8) {
        *(bf16x8*)(da + (size_t)i * 8) = load8(a + (size_t)i * 8);
    } else if ((i -= na8) < nb8) {
        *(bf16x8*)(db + (size_t)i * 8) = load8(b + (size_t)i * 8);
    } else if ((i -= nb8) < nc8) {
        *(bf16x8*)(dc + (size_t)i * 8) = load8(c + (size_t)i * 8);
    }
}

// ---------------------------------------------------------------------------
// 256x256 8-phase GEMM (bf16 x bf16): C = A(MxK) * B(NxK)^T + bias.
// LDS swizzle v2: within each 16x32 (1024B) subtile, element (r,c) at byte
//   (r&15)*64 + ((c&31)*2 ^ (((r>>1)&3)<<4))
// -> a wave's b128 column-slice read (row=m16 varies, 16B slot=quad) hits each
//    bank at most 2-way (free), vs 8-way with the previous (r&8)<<2 swizzle.
// global_load_lds writes linearly; per-lane GLOBAL source is inverse-permuted
// with the same XOR (16B-aligned, so 16B load granularity is preserved).
// ---------------------------------------------------------------------------
#define GB_REG 65536

__device__ __forceinline__ int half_off(int buf, int half) {
    return buf * 32768 + half * 16384;
}

template <typename TC>
__global__ __launch_bounds__(512) void gemm256(
    const __hip_bfloat16* __restrict__ A, const __hip_bfloat16* __restrict__ B,
    const float* __restrict__ bias, TC* __restrict__ C, int M, int N, int K)
{
    __shared__ char smem[131072];

    const int tid  = threadIdx.x;
    const int lane = tid & 63;
    const int wid  = tid >> 6;
    const int quad = lane >> 4;
    const int m16  = lane & 15;
    const int wmg  = wid >> 2;       // 0..1 -> A half (M 128-row group)
    const int wng  = wid & 3;        // 0..3 -> N 64-col group
    const int bhalf = wng >> 1;      // B half
    const int bsub  = (wng & 1) * 4; // subtile row base within B half

    // XCD-chunked block swizzle (bijective: nwg % 8 == 0 for our shapes)
    const int gx  = gridDim.x;
    const int nwg = gx * gridDim.y;
    int lin = blockIdx.y * gx + blockIdx.x;
    if ((nwg & 7) == 0) {
        int q = nwg >> 3;
        lin = (lin & 7) * q + (lin >> 3);
    }
    const int bn = lin % gx, bm = lin / gx;
    const int mBase = bm * 256, nBase = bn * 256;

    // swizzled ds_read offset within a subtile (v2 swizzle)
    const int roff = (m16 << 6) | ((quad * 16) ^ (((m16 >> 1) & 3) << 4));

    // staging: thread's linear LDS slot X = l*8192 + tid*16 -> source (r,c)
    int r_s[2], c_s[2];
    #pragma unroll
    for (int l = 0; l < 2; ++l) {
        int sub = l * 8 + wid;
        int r16 = (tid >> 2) & 15;
        int cb  = ((tid & 3) * 16) ^ (((r16 >> 1) & 3) << 4);
        r_s[l] = (sub >> 1) * 16 + r16;
        c_s[l] = (sub & 1) * 32 + (cb >> 1);
    }

    const __hip_bfloat16* Ab = A + (size_t)mBase * K;
    const __hip_bfloat16* Bb = B + (size_t)nBase * K;

    auto stage = [&](int region, const __hip_bfloat16* base, int buf, int half, int tile) {
        const __hip_bfloat16* gb = base + (size_t)(half * 128) * K + tile * 64;
        #pragma unroll
        for (int l = 0; l < 2; ++l) {
            const __hip_bfloat16* g = gb + (size_t)r_s[l] * K + c_s[l];
            short* lb = (short*)(smem + region + half_off(buf, half) + l * 8192 + wid * 1024);
            __builtin_amdgcn_global_load_lds(
                (__attribute__((address_space(1))) void*)g,
                (__attribute__((address_space(3))) void*)lb, 16, 0, 0);
        }
    };

    f32x4 acc[8][4] = {};
    bf16x8 afr[4][2];       // 4 m-frags x 2 k-slices (current m-quartet)
    bf16x8 bfr[2][2][2];    // [n-pair g][j][ks] -- both n-pairs stay live

    auto LD_A = [&](int buf, int g) {
        const char* base = smem + half_off(buf, wmg) + (g ? 8192 : 0);
        #pragma unroll
        for (int m = 0; m < 4; ++m)
            #pragma unroll
            for (int ks = 0; ks < 2; ++ks)
                afr[m][ks] = *(const bf16x8*)(base + ((m * 2 + ks) << 10) + roff);
    };
    auto LD_B = [&](int buf, int g) {
        const char* base = smem + GB_REG + half_off(buf, bhalf) + ((bsub + g * 2) << 11);
        #pragma unroll
        for (int j = 0; j < 2; ++j)
            #pragma unroll
            for (int ks = 0; ks < 2; ++ks)
                bfr[g][j][ks] = *(const bf16x8*)(base + ((j * 2 + ks) << 10) + roff);
    };
    auto MM = [&](int mo, int g) {
        #pragma unroll
        for (int m = 0; m < 4; ++m)
            #pragma unroll
            for (int j = 0; j < 2; ++j)
                #pragma unroll
                for (int ks = 0; ks < 2; ++ks)
                    acc[mo + m][g * 2 + j] = __builtin_amdgcn_mfma_f32_16x16x32_bf16(
                        afr[m][ks], bfr[g][j][ks], acc[mo + m][g * 2 + j], 0, 0, 0);
    };

#define SBAR() __builtin_amdgcn_s_barrier()
#define WAIT_LGKM0() do { asm volatile("s_waitcnt lgkmcnt(0)" ::: "memory"); \
                          __builtin_amdgcn_sched_barrier(0); } while (0)
#define WAIT_VM4()   do { asm volatile("s_waitcnt vmcnt(4)"   ::: "memory"); \
                          __builtin_amdgcn_sched_barrier(0); } while (0)

    const int NT = K >> 6;

    // prologue: tile0 -> buf0 (all 4 halves), tile1 -> buf1 (B.h0, A.h0)
    stage(GB_REG, Bb, 0, 0, 0);
    stage(0,      Ab, 0, 0, 0);
    stage(GB_REG, Bb, 0, 1, 0);
    stage(0,      Ab, 0, 1, 0);
    stage(GB_REG, Bb, 1, 0, 1);
    stage(0,      Ab, 1, 0, 1);
    WAIT_VM4();      // tile0's 8 loads done; tile1's 4 may fly
    SBAR();

    for (int i = 0; i < (NT >> 1); ++i) {
        const int to = 2 * i + 1;
        const int t2 = min(2 * i + 2, NT - 1);
        const int t3 = min(2 * i + 3, NT - 1);
        // P0: quadrant (m0-3, n0-1) of even tile (buf0)
        LD_A(0, 0); LD_B(0, 0);
        stage(GB_REG, Bb, 1, 1, to);
        SBAR(); WAIT_LGKM0();
        __builtin_amdgcn_s_setprio(1); MM(0, 0); __builtin_amdgcn_s_setprio(0);
        SBAR();
        // P1: (m0-3, n2-3)
        LD_B(0, 1);
        stage(0, Ab, 1, 1, to);
        SBAR(); WAIT_LGKM0();
        __builtin_amdgcn_s_setprio(1); MM(0, 1); __builtin_amdgcn_s_setprio(0);
        SBAR();
        // P2: (m4-7, n2-3)
        LD_A(0, 1);
        stage(GB_REG, Bb, 0, 0, t2);
        SBAR(); WAIT_LGKM0();
        __builtin_amdgcn_s_setprio(1); MM(4, 1); __builtin_amdgcn_s_setprio(0);
        SBAR();
        // P3: (m4-7, n0-1) register-only; gate odd-tile arrival (counted vmcnt)
        stage(0, Ab, 0, 0, t2);
        WAIT_VM4();
        SBAR();
        __builtin_amdgcn_s_setprio(1); MM(4, 0); __builtin_amdgcn_s_setprio(0);
        SBAR();
        // P4: odd tile (buf1), (m0-3, n0-1)
        LD_A(1, 0); LD_B(1, 0);
        stage(GB_REG, Bb, 0, 1, t2);
        SBAR(); WAIT_LGKM0();
        __builtin_amdgcn_s_setprio(1); MM(0, 0); __builtin_amdgcn_s_setprio(0);
        SBAR();
        // P5: (m0-3, n2-3)
        LD_B(1, 1);
        stage(0, Ab, 0, 1, t2);
        SBAR(); WAIT_LGKM0();
        __builtin_amdgcn_s_setprio(1); MM(0, 1); __builtin_amdgcn_s_setprio(0);
        SBAR();
        // P6: (m4-7, n2-3)
        LD_A(1, 1);
        stage(GB_REG, Bb, 1, 0, t3);
        SBAR(); WAIT_LGKM0();
        __builtin_amdgcn_s_setprio(1); MM(4, 1); __builtin_amdgcn_s_setprio(0);
        SBAR();
        // P7: (m4-7, n0-1) register-only; gate even-tile arrival
        stage(0, Ab, 1, 0, t3);
        WAIT_VM4();
        SBAR();
        __builtin_amdgcn_s_setprio(1); MM(4, 0); __builtin_amdgcn_s_setprio(0);
        SBAR();
    }

#undef SBAR
#undef WAIT_LGKM0
#undef WAIT_VM4

    float bv[4];
    #pragma unroll
    for (int j = 0; j < 4; ++j)
        bv[j] = bias[nBase + wng * 64 + j * 16 + m16];

    #pragma unroll
    for (int mf = 0; mf < 8; ++mf) {
        #pragma unroll
        for (int j = 0; j < 4; ++j) {
            const int col = nBase + wng * 64 + j * 16 + m16;
            #pragma unroll
            for (int r = 0; r < 4; ++r) {
                const int row = mBase + wmg * 128 + mf * 16 + quad * 4 + r;
                store_out(&C[(size_t)row * N + col], acc[mf][j][r] + bv[j]);
            }
        }
    }
}

// ---------------------------------------------------------------------------
// Fallback GEMM (fp32 inputs converted inline) — safety net if ws too small
// ---------------------------------------------------------------------------
#define LDSS 40

template <typename TA, typename TB, typename TC>
__global__ __launch_bounds__(256) void gemm_bt_bias(
    const TA* __restrict__ A, const TB* __restrict__ B,
    const float* __restrict__ bias, TC* __restrict__ C, int M, int N, int K)
{
    __shared__ short As[128 * LDSS];
    __shared__ short Bs[128 * LDSS];

    const int tid  = threadIdx.x;
    const int lane = tid & 63;
    const int wid  = tid >> 6;
    const int quad = lane >> 4;
    const int m16  = lane & 15;

    const int mBase = blockIdx.y * 128;
    const int nBase = blockIdx.x * 128;
    const int wm = (wid >> 1) * 64;
    const int wn = (wid & 1) * 64;

    f32x4 acc[4][4] = {};
    const int srow = tid >> 2;
    const int sgrp = (tid & 3) * 8;

    for (int kt = 0; kt < K; kt += 32) {
        __syncthreads();
        for (int p = 0; p < 2; ++p) {
            int r = srow + p * 64;
            *(bf16x8*)(&As[r * LDSS + sgrp]) =
                load8(A + (size_t)(mBase + r) * K + kt + sgrp);
            *(bf16x8*)(&Bs[r * LDSS + sgrp]) =
                load8(B + (size_t)(nBase + r) * K + kt + sgrp);
        }
        __syncthreads();

        bf16x8 afr[4], bfr[4];
        #pragma unroll
        for (int i = 0; i < 4; ++i)
            afr[i] = *(const bf16x8*)(&As[(wm + 16 * i + m16) * LDSS + quad * 8]);
        #pragma unroll
        for (int j = 0; j < 4; ++j)
            bfr[j] = *(const bf16x8*)(&Bs[(wn + 16 * j + m16) * LDSS + quad * 8]);
        #pragma unroll
        for (int i = 0; i < 4; ++i)
            #pragma unroll
            for (int j = 0; j < 4; ++j)
                acc[i][j] = __builtin_amdgcn_mfma_f32_16x16x32_bf16(
                    afr[i], bfr[j], acc[i][j], 0, 0, 0);
    }

    float bv[4];
    #pragma unroll
    for (int j = 0; j < 4; ++j)
        bv[j] = bias[nBase + wn + 16 * j + m16];

    #pragma unroll
    for (int i = 0; i < 4; ++i)
        #pragma unroll
        for (int j = 0; j < 4; ++j) {
            int col = nBase + wn + 16 * j + m16;
            #pragma unroll
            for (int r = 0; r < 4; ++r) {
                int row = mBase + wm + 16 * i + quad * 4 + r;
                store_out(&C[(size_t)row * N + col], acc[i][j][r] + bv[j]);
            }
        }
}

// ---------------------------------------------------------------------------
// RoPE in-place on q (heads 0..23) and k (cols 3072..3327), 8 elems/thread
// ---------------------------------------------------------------------------
__global__ void rope_kernel(__hip_bfloat16* __restrict__ qkv,
                            const float* __restrict__ cosb,
                            const float* __restrict__ sinb, int T)
{
    int idx = blockIdx.x * 256 + threadIdx.x;          // (t, h, j): j = d/8
    int total = T * 26 * 8;
    if (idx >= total) return;
    int j = idx & 7;
    int h = (idx >> 3) % 26;
    int t = idx / (26 * 8);
    int col = (h < 24) ? h * 128 : 3072 + (h - 24) * 128;
    int d0 = j * 8;
    size_t base = (size_t)t * 3584 + col + d0;
    bf16x8 x1 = *(const bf16x8*)((const short*)qkv + base);
    bf16x8 x2 = *(const bf16x8*)((const short*)qkv + base + 64);
    float4 c0 = *(const float4*)(cosb + t * 64 + d0);
    float4 c1 = *(const float4*)(cosb + t * 64 + d0 + 4);
    float4 s0 = *(const float4*)(sinb + t * 64 + d0);
    float4 s1 = *(const float4*)(sinb + t * 64 + d0 + 4);
    float cc[8] = {c0.x, c0.y, c0.z, c0.w, c1.x, c1.y, c1.z, c1.w};
    float ss[8] = {s0.x, s0.y, s0.z, s0.w, s1.x, s1.y, s1.z, s1.w};
    bf16x8 o1, o2;
    #pragma unroll
    for (int i = 0; i < 8; ++i) {
        float f1 = bf_bits2f(x1[i]);
        float f2 = bf_bits2f(x2[i]);
        o1[i] = f2bf_bits(f1 * cc[i] - f2 * ss[i]);
        o2[i] = f2bf_bits(f2 * cc[i] + f1 * ss[i]);
    }
    *(bf16x8*)((short*)qkv + base)      = o1;
    *(bf16x8*)((short*)qkv + base + 64) = o2;
}

// ---------------------------------------------------------------------------
// Flash attention v6 = v3 (known-good 152us structure) + two minimal tweaks:
//  - V global loads hoisted ABOVE the first barrier (raw s_barrier, no vmcnt
//    drain) so V latency overlaps the barrier wait, not the critical path.
//  - LPT heavy-first block remap (descending qb) to cut the drain tail.
// Everything else identical to v3: QBLK=128, single Vt, K direct from global.
// ---------------------------------------------------------------------------
#define SM_SHIFT 12.0f

__global__ __launch_bounds__(256, 3) void attn_kernel(
    const __hip_bfloat16* __restrict__ qkv,  // T x 3584 (rope applied)
    __hip_bfloat16* __restrict__ out,        // T x 3072
    const int* __restrict__ seq_len_p, const int* __restrict__ window_p)
{
    const int S = seq_len_p[0];
    const int window = window_p[0];
    const float scale = 0.088388347648318447f;  // 1/sqrt(128)

    const int h   = blockIdx.y;
    const int kvh = h / 12;
    const int tid  = threadIdx.x;
    const int lane = tid & 63;
    const int wid  = tid >> 6;
    const int quad = lane >> 4;
    const int m16  = lane & 15;

    // heavy-first remap: descending qb within each batch (LPT scheduling)
    const int nbb = S >> 7;                  // q-blocks (128 rows) per batch
    const int b   = blockIdx.x / nbb;
    const int ib  = blockIdx.x - b * nbb;
    const int qb  = (nbb - 1 - ib) << 7;
    const int qb_global = b * S + qb;

    __shared__ short Vt[128 * 72];      // V^T: V[key][d] at [d*72 + key + ((d>>3)&1)*32]
    __shared__ short Ps[4][32 * 40];    // per-wave P [q][key], stride 40

    const size_t kvrow0 = (size_t)(b * S) * 3584 + 3072 + kvh * 128;

    bf16x8 qf[2][4];
    {
        const __hip_bfloat16* qp =
            qkv + (size_t)(qb_global + wid * 32 + m16) * 3584 + h * 128;
        #pragma unroll
        for (int qt = 0; qt < 2; ++qt)
            #pragma unroll
            for (int dc = 0; dc < 4; ++dc)
                qf[qt][dc] = *(const bf16x8*)(qp + qt * 16 * 3584 + dc * 32 + quad * 8);
    }

    f32x4 accO[2][8] = {};
    float lqt[2] = {0.f, 0.f};

    int ka0 = qb - window + 1;
    if (ka0 < 0) ka0 = 0;
    ka0 &= ~31;
    const int kend = qb + 128;
    const int niter = (kend - ka0) >> 5;

    // staging geometry (per thread): 2 chunks, each = one V row-slice of 8
    const int skey = tid & 31;          // key within 32-tile
    const int sgg0 = tid >> 5;          // 0..7  (chunk 0 d-group)
    const int sgg1 = sgg0 + 8;          // 8..15 (chunk 1 d-group)

    for (int it = 0; it < niter; ++it) {
        const int kt = ka0 + it * 32;

        // issue V loads BEFORE B1 -- they fly while waves drain into the barrier
        bf16x8 v0 = *(const bf16x8*)(qkv + kvrow0 + (size_t)(kt + skey) * 3584 + 256 + sgg0 * 8);
        bf16x8 v1 = *(const bf16x8*)(qkv + kvrow0 + (size_t)(kt + skey) * 3584 + 256 + sgg1 * 8);

        // B1: all waves' previous-iter PV reads of Vt are complete (data-dep
        // ordered before this barrier); raw barrier keeps v0/v1 in flight
        __builtin_amdgcn_s_barrier();

        // transpose-write V^T (compiler inserts vmcnt wait for v0/v1)
        {
            short* dst0 = &Vt[(sgg0 * 8) * 72 + skey + (sgg0 & 1) * 32];
            short* dst1 = &Vt[(sgg1 * 8) * 72 + skey + (sgg1 & 1) * 32];
            #pragma unroll
            for (int i2 = 0; i2 < 8; ++i2) dst0[i2 * 72] = v0[i2];
            #pragma unroll
            for (int i2 = 0; i2 < 8; ++i2) dst1[i2 * 72] = v1[i2];
        }
        asm volatile("s_waitcnt lgkmcnt(0)" ::: "memory");
        // B2: Vt ready for all waves
        __builtin_amdgcn_s_barrier();
        __builtin_amdgcn_sched_barrier(0);

        // S^T = K * Q^T (K frags direct from global, L2-hot)
        f32x4 sacc[2][2] = {};   // [st][qt]
        #pragma unroll
        for (int st = 0; st < 2; ++st) {
            const __hip_bfloat16* kp =
                qkv + kvrow0 + (size_t)(kt + st * 16 + m16) * 3584;
            #pragma unroll
            for (int dc = 0; dc < 4; ++dc) {
                bf16x8 kf = *(const bf16x8*)(kp + dc * 32 + quad * 8);
                sacc[st][0] = __builtin_amdgcn_mfma_f32_16x16x32_bf16(
                    kf, qf[0][dc], sacc[st][0], 0, 0, 0);
                sacc[st][1] = __builtin_amdgcn_mfma_f32_16x16x32_bf16(
                    kf, qf[1][dc], sacc[st][1], 0, 0, 0);
            }
        }

        // fixed-shift softmax: p = exp(s*scale - SHIFT); no rescaling ever.
        // S^T C-layout: col m16 = q, row quad*4 + r + st*16 = key
        #pragma unroll
        for (int qt = 0; qt < 2; ++qt) {
            const int qmin = qb + wid * 32 + qt * 16;     // wave-uniform
            short* prow = &Ps[wid][(qt * 16 + m16) * 40];
            float psum = 0.f;
            if (kt <= qmin - 31 && kt >= qmin + 16 - window) {
                // interior: all 32 keys valid for all 16 q
                #pragma unroll
                for (int st = 0; st < 2; ++st)
                    #pragma unroll
                    for (int r = 0; r < 4; ++r) {
                        float pp = __expf(fminf(
                            sacc[st][qt][r] * scale - SM_SHIFT, 80.f));
                        psum += pp;
                        prow[st * 16 + quad * 4 + r] = f2bf_bits(pp);
                    }
            } else {
                const int dl_base = (qmin + m16) - (kt + quad * 4);
                #pragma unroll
                for (int st = 0; st < 2; ++st)
                    #pragma unroll
                    for (int r = 0; r < 4; ++r) {
                        int dl = dl_base - st * 16 - r;
                        float pp = ((unsigned)dl < (unsigned)window)
                            ? __expf(fminf(sacc[st][qt][r] * scale - SM_SHIFT, 80.f))
                            : 0.f;
                        psum += pp;
                        prow[st * 16 + quad * 4 + r] = f2bf_bits(pp);
                    }
            }
            psum += __shfl_xor(psum, 16, 64);
            psum += __shfl_xor(psum, 32, 64);
            lqt[qt] += psum;
        }

        // PV: A = P (wave-private LDS), B = V^T frag
        bf16x8 pf0 = *(const bf16x8*)(&Ps[wid][(0  + m16) * 40 + quad * 8]);
        bf16x8 pf1 = *(const bf16x8*)(&Ps[wid][(16 + m16) * 40 + quad * 8]);
        __builtin_amdgcn_s_setprio(1);
        #pragma unroll
        for (int dt = 0; dt < 8; ++dt) {
            int row = dt * 16 + m16;
            bf16x8 vf = *(const bf16x8*)(&Vt[row * 72 + quad * 8 + ((row >> 3) & 1) * 32]);
            accO[0][dt] = __builtin_amdgcn_mfma_f32_16x16x32_bf16(pf0, vf, accO[0][dt], 0, 0, 0);
            accO[1][dt] = __builtin_amdgcn_mfma_f32_16x16x32_bf16(pf1, vf, accO[1][dt], 0, 0, 0);
        }
        __builtin_amdgcn_s_setprio(0);
    }

    // epilogue: O /= l
    #pragma unroll
    for (int qt = 0; qt < 2; ++qt) {
        float li[4];
        #pragma unroll
        for (int r = 0; r < 4; ++r)
            li[r] = 1.0f / __shfl(lqt[qt], quad * 4 + r, 64);
        #pragma unroll
        for (int r = 0; r < 4; ++r) {
            int t = qb_global + wid * 32 + qt * 16 + quad * 4 + r;
            __hip_bfloat16* op = out + (size_t)t * 3072 + h * 128 + m16;
            #pragma unroll
            for (int dt = 0; dt < 8; ++dt)
                op[dt * 16] = __float2bfloat16(accO[qt][dt][r] * li[r]);
        }
    }
}

// ---------------------------------------------------------------------------
extern "C" void kernel_launch(void* const* d_in, const int* in_sizes, int n_in,
                              void* d_out, int out_size, void* d_ws, size_t ws_size,
                              hipStream_t stream) {
    const float* hidden = (const float*)d_in[0];
    const float* w_qkv  = (const float*)d_in[1];
    const float* b_qkv  = (const float*)d_in[2];
    const float* w_o    = (const float*)d_in[3];
    const float* b_o    = (const float*)d_in[4];
    const float* cosb   = (const float*)d_in[5];
    const float* sinb   = (const float*)d_in[6];
    const int* seq_len_p = (const int*)d_in[7];
    const int* window_p  = (const int*)d_in[8];

    const int HID  = in_sizes[4];            // 3072
    const int NQKV = in_sizes[2];            // 3584
    const int T    = in_sizes[0] / HID;      // 4096

    size_t off = 0;
    auto alloc = [&](size_t bytes) {
        char* p = (char*)d_ws + off;
        off = (off + bytes + 255) & ~(size_t)255;
        return p;
    };
    __hip_bfloat16* qkv      = (__hip_bfloat16*)alloc((size_t)T * NQKV * 2);
    __hip_bfloat16* attn_out = (__hip_bfloat16*)alloc((size_t)T * HID * 2);
    __hip_bfloat16* hid_bf = (__hip_bfloat16*)alloc((size_t)T * HID * 2);
    __hip_bfloat16* wq_bf  = (__hip_bfloat16*)alloc((size_t)NQKV * HID * 2);
    __hip_bfloat16* wo_bf  = (__hip_bfloat16*)alloc((size_t)HID * HID * 2);
    const bool pre = (ws_size >= off);
    const bool big = pre && (T % 256 == 0) && (NQKV % 256 == 0) &&
                     (HID % 256 == 0) && (HID % 64 == 0);

    dim3 blk(256);

    if (big) {
        int n8h = T * HID / 8, n8q = NQKV * HID / 8, n8o = HID * HID / 8;
        int n8 = n8h + n8q + n8o;
        cvt3_f32_bf16<<<dim3((n8 + 255) / 256), blk, 0, stream>>>(
            hidden, (short*)hid_bf, n8h, w_qkv, (short*)wq_bf, n8q,
            w_o, (short*)wo_bf, n8o);
        gemm256<__hip_bfloat16><<<dim3(NQKV / 256, T / 256), dim3(512), 0, stream>>>(
            hid_bf, wq_bf, b_qkv, qkv, T, NQKV, HID);
    } else {
        gemm_bt_bias<float, float, __hip_bfloat16>
            <<<dim3(NQKV / 128, T / 128), blk, 0, stream>>>(
            hidden, w_qkv, b_qkv, qkv, T, NQKV, HID);
    }

    int total = T * 26 * 8;
    rope_kernel<<<dim3((total + 255) / 256), blk, 0, stream>>>(qkv, cosb, sinb, T);

    attn_kernel<<<dim3(T / 128, 24), blk, 0, stream>>>(qkv, attn_out, seq_len_p, window_p);

    if (big) {
        gemm256<float><<<dim3(HID / 256, T / 256), dim3(512), 0, stream>>>(
            attn_out, wo_bf, b_o, (float*)d_out, T, HID, HID);
    } else {
        gemm_bt_bias<__hip_bfloat16, float, float>
            <<<dim3(HID / 128, T / 128), blk, 0, stream>>>(
            attn_out, w_o, b_o, (float*)d_out, T, HID, HID);
    }
}

// Round 5
// 477.406 us; speedup vs baseline: 1.3490x; 1.0070x over previous
//
#include <hip/hip_runtime.h>
#include <hip/hip_bf16.h>

typedef __attribute__((ext_vector_type(8))) short bf16x8;
typedef __attribute__((ext_vector_type(4))) float f32x4;

__device__ __forceinline__ short f2bf_bits(float f) {
    __hip_bfloat16 h = __float2bfloat16(f);
    short s;
    __builtin_memcpy(&s, &h, 2);
    return s;
}

__device__ __forceinline__ float bf_bits2f(short s) {
    unsigned int u = ((unsigned int)(unsigned short)s) << 16;
    float f;
    __builtin_memcpy(&f, &u, 4);
    return f;
}

__device__ __forceinline__ bf16x8 load8(const float* p) {
    float4 a = *(const float4*)p;
    float4 b = *(const float4*)(p + 4);
    bf16x8 r;
    r[0] = f2bf_bits(a.x); r[1] = f2bf_bits(a.y);
    r[2] = f2bf_bits(a.z); r[3] = f2bf_bits(a.w);
    r[4] = f2bf_bits(b.x); r[5] = f2bf_bits(b.y);
    r[6] = f2bf_bits(b.z); r[7] = f2bf_bits(b.w);
    return r;
}
__device__ __forceinline__ bf16x8 load8(const __hip_bfloat16* p) {
    return *(const bf16x8*)p;
}

__device__ __forceinline__ void store_out(__hip_bfloat16* p, float v) {
    *p = __float2bfloat16(v);
}
__device__ __forceinline__ void store_out(float* p, float v) { *p = v; }

// ---------------------------------------------------------------------------
// merged f32 -> bf16 bulk convert of three buffers (8 elems/thread)
// ---------------------------------------------------------------------------
__global__ void cvt3_f32_bf16(const float* __restrict__ a, short* __restrict__ da, int na8,
                              const float* __restrict__ b, short* __restrict__ db, int nb8,
                              const float* __restrict__ c, short* __restrict__ dc, int nc8) {
    int i = blockIdx.x * 256 + threadIdx.x;
    if (i < na8) {
        *(bf16x8*)(da + (size_t)i * 8) = load8(a + (size_t)i * 8);
    } else if ((i -= na8) < nb8) {
        *(bf16x8*)(db + (size_t)i * 8) = load8(b + (size_t)i * 8);
    } else if ((i -= nb8) < nc8) {
        *(bf16x8*)(dc + (size_t)i * 8) = load8(c + (size_t)i * 8);
    }
}

// ---------------------------------------------------------------------------
// 256x256 8-phase GEMM (bf16 x bf16): C = A(MxK) * B(NxK)^T + bias.
// T2-style LDS swizzle + T3/T4 counted-vmcnt 8-phase pipeline + T5 setprio.
// 512 threads = 8 waves (2M x 4N), per-wave 128x64 output, BK=64, 128 KiB LDS.
// ---------------------------------------------------------------------------
#define GB_REG 65536

__device__ __forceinline__ int half_off(int buf, int half) {
    return buf * 32768 + half * 16384;
}

template <typename TC>
__global__ __launch_bounds__(512) void gemm256(
    const __hip_bfloat16* __restrict__ A, const __hip_bfloat16* __restrict__ B,
    const float* __restrict__ bias, TC* __restrict__ C, int M, int N, int K)
{
    __shared__ char smem[131072];

    const int tid  = threadIdx.x;
    const int lane = tid & 63;
    const int wid  = tid >> 6;
    const int quad = lane >> 4;
    const int m16  = lane & 15;
    const int wmg  = wid >> 2;       // 0..1 -> A half (M 128-row group)
    const int wng  = wid & 3;        // 0..3 -> N 64-col group
    const int bhalf = wng >> 1;      // B half
    const int bsub  = (wng & 1) * 4; // subtile row base within B half

    // XCD-chunked block swizzle (bijective: nwg % 8 == 0 for our shapes)
    const int gx  = gridDim.x;
    const int nwg = gx * gridDim.y;
    int lin = blockIdx.y * gx + blockIdx.x;
    if ((nwg & 7) == 0) {
        int q = nwg >> 3;
        lin = (lin & 7) * q + (lin >> 3);
    }
    const int bn = lin % gx, bm = lin / gx;
    const int mBase = bm * 256, nBase = bn * 256;

    // swizzled ds_read offset within a subtile (v2 swizzle)
    const int roff = (m16 << 6) | ((quad * 16) ^ (((m16 >> 1) & 3) << 4));

    // staging: thread's linear LDS slot X = l*8192 + tid*16 -> source (r,c)
    int r_s[2], c_s[2];
    #pragma unroll
    for (int l = 0; l < 2; ++l) {
        int sub = l * 8 + wid;
        int r16 = (tid >> 2) & 15;
        int cb  = ((tid & 3) * 16) ^ (((r16 >> 1) & 3) << 4);
        r_s[l] = (sub >> 1) * 16 + r16;
        c_s[l] = (sub & 1) * 32 + (cb >> 1);
    }

    const __hip_bfloat16* Ab = A + (size_t)mBase * K;
    const __hip_bfloat16* Bb = B + (size_t)nBase * K;

    auto stage = [&](int region, const __hip_bfloat16* base, int buf, int half, int tile) {
        const __hip_bfloat16* gb = base + (size_t)(half * 128) * K + tile * 64;
        #pragma unroll
        for (int l = 0; l < 2; ++l) {
            const __hip_bfloat16* g = gb + (size_t)r_s[l] * K + c_s[l];
            short* lb = (short*)(smem + region + half_off(buf, half) + l * 8192 + wid * 1024);
            __builtin_amdgcn_global_load_lds(
                (__attribute__((address_space(1))) void*)g,
                (__attribute__((address_space(3))) void*)lb, 16, 0, 0);
        }
    };

    f32x4 acc[8][4] = {};
    bf16x8 afr[4][2];       // 4 m-frags x 2 k-slices (current m-quartet)
    bf16x8 bfr[2][2][2];    // [n-pair g][j][ks] -- both n-pairs stay live

    auto LD_A = [&](int buf, int g) {
        const char* base = smem + half_off(buf, wmg) + (g ? 8192 : 0);
        #pragma unroll
        for (int m = 0; m < 4; ++m)
            #pragma unroll
            for (int ks = 0; ks < 2; ++ks)
                afr[m][ks] = *(const bf16x8*)(base + ((m * 2 + ks) << 10) + roff);
    };
    auto LD_B = [&](int buf, int g) {
        const char* base = smem + GB_REG + half_off(buf, bhalf) + ((bsub + g * 2) << 11);
        #pragma unroll
        for (int j = 0; j < 2; ++j)
            #pragma unroll
            for (int ks = 0; ks < 2; ++ks)
                bfr[g][j][ks] = *(const bf16x8*)(base + ((j * 2 + ks) << 10) + roff);
    };
    auto MM = [&](int mo, int g) {
        #pragma unroll
        for (int m = 0; m < 4; ++m)
            #pragma unroll
            for (int j = 0; j < 2; ++j)
                #pragma unroll
                for (int ks = 0; ks < 2; ++ks)
                    acc[mo + m][g * 2 + j] = __builtin_amdgcn_mfma_f32_16x16x32_bf16(
                        afr[m][ks], bfr[g][j][ks], acc[mo + m][g * 2 + j], 0, 0, 0);
    };

#define SBAR() __builtin_amdgcn_s_barrier()
#define WAIT_LGKM0() do { asm volatile("s_waitcnt lgkmcnt(0)" ::: "memory"); \
                          __builtin_amdgcn_sched_barrier(0); } while (0)
#define WAIT_VM4()   do { asm volatile("s_waitcnt vmcnt(4)"   ::: "memory"); \
                          __builtin_amdgcn_sched_barrier(0); } while (0)

    const int NT = K >> 6;

    // prologue: tile0 -> buf0 (all 4 halves), tile1 -> buf1 (B.h0, A.h0)
    stage(GB_REG, Bb, 0, 0, 0);
    stage(0,      Ab, 0, 0, 0);
    stage(GB_REG, Bb, 0, 1, 0);
    stage(0,      Ab, 0, 1, 0);
    stage(GB_REG, Bb, 1, 0, 1);
    stage(0,      Ab, 1, 0, 1);
    WAIT_VM4();      // tile0's 8 loads done; tile1's 4 may fly
    SBAR();

    for (int i = 0; i < (NT >> 1); ++i) {
        const int to = 2 * i + 1;
        const int t2 = min(2 * i + 2, NT - 1);
        const int t3 = min(2 * i + 3, NT - 1);
        // P0: quadrant (m0-3, n0-1) of even tile (buf0)
        LD_A(0, 0); LD_B(0, 0);
        stage(GB_REG, Bb, 1, 1, to);
        SBAR(); WAIT_LGKM0();
        __builtin_amdgcn_s_setprio(1); MM(0, 0); __builtin_amdgcn_s_setprio(0);
        SBAR();
        // P1: (m0-3, n2-3)
        LD_B(0, 1);
        stage(0, Ab, 1, 1, to);
        SBAR(); WAIT_LGKM0();
        __builtin_amdgcn_s_setprio(1); MM(0, 1); __builtin_amdgcn_s_setprio(0);
        SBAR();
        // P2: (m4-7, n2-3)
        LD_A(0, 1);
        stage(GB_REG, Bb, 0, 0, t2);
        SBAR(); WAIT_LGKM0();
        __builtin_amdgcn_s_setprio(1); MM(4, 1); __builtin_amdgcn_s_setprio(0);
        SBAR();
        // P3: (m4-7, n0-1) register-only; gate odd-tile arrival (counted vmcnt)
        stage(0, Ab, 0, 0, t2);
        WAIT_VM4();
        SBAR();
        __builtin_amdgcn_s_setprio(1); MM(4, 0); __builtin_amdgcn_s_setprio(0);
        SBAR();
        // P4: odd tile (buf1), (m0-3, n0-1)
        LD_A(1, 0); LD_B(1, 0);
        stage(GB_REG, Bb, 0, 1, t2);
        SBAR(); WAIT_LGKM0();
        __builtin_amdgcn_s_setprio(1); MM(0, 0); __builtin_amdgcn_s_setprio(0);
        SBAR();
        // P5: (m0-3, n2-3)
        LD_B(1, 1);
        stage(0, Ab, 0, 1, t2);
        SBAR(); WAIT_LGKM0();
        __builtin_amdgcn_s_setprio(1); MM(0, 1); __builtin_amdgcn_s_setprio(0);
        SBAR();
        // P6: (m4-7, n2-3)
        LD_A(1, 1);
        stage(GB_REG, Bb, 1, 0, t3);
        SBAR(); WAIT_LGKM0();
        __builtin_amdgcn_s_setprio(1); MM(4, 1); __builtin_amdgcn_s_setprio(0);
        SBAR();
        // P7: (m4-7, n0-1) register-only; gate even-tile arrival
        stage(0, Ab, 1, 0, t3);
        WAIT_VM4();
        SBAR();
        __builtin_amdgcn_s_setprio(1); MM(4, 0); __builtin_amdgcn_s_setprio(0);
        SBAR();
    }

#undef SBAR
#undef WAIT_LGKM0
#undef WAIT_VM4

    float bv[4];
    #pragma unroll
    for (int j = 0; j < 4; ++j)
        bv[j] = bias[nBase + wng * 64 + j * 16 + m16];

    #pragma unroll
    for (int mf = 0; mf < 8; ++mf) {
        #pragma unroll
        for (int j = 0; j < 4; ++j) {
            const int col = nBase + wng * 64 + j * 16 + m16;
            #pragma unroll
            for (int r = 0; r < 4; ++r) {
                const int row = mBase + wmg * 128 + mf * 16 + quad * 4 + r;
                store_out(&C[(size_t)row * N + col], acc[mf][j][r] + bv[j]);
            }
        }
    }
}

// ---------------------------------------------------------------------------
// Fallback GEMM (fp32 inputs converted inline) — safety net if ws too small
// ---------------------------------------------------------------------------
#define LDSS 40

template <typename TA, typename TB, typename TC>
__global__ __launch_bounds__(256) void gemm_bt_bias(
    const TA* __restrict__ A, const TB* __restrict__ B,
    const float* __restrict__ bias, TC* __restrict__ C, int M, int N, int K)
{
    __shared__ short As[128 * LDSS];
    __shared__ short Bs[128 * LDSS];

    const int tid  = threadIdx.x;
    const int lane = tid & 63;
    const int wid  = tid >> 6;
    const int quad = lane >> 4;
    const int m16  = lane & 15;

    const int mBase = blockIdx.y * 128;
    const int nBase = blockIdx.x * 128;
    const int wm = (wid >> 1) * 64;
    const int wn = (wid & 1) * 64;

    f32x4 acc[4][4] = {};
    const int srow = tid >> 2;
    const int sgrp = (tid & 3) * 8;

    for (int kt = 0; kt < K; kt += 32) {
        __syncthreads();
        for (int p = 0; p < 2; ++p) {
            int r = srow + p * 64;
            *(bf16x8*)(&As[r * LDSS + sgrp]) =
                load8(A + (size_t)(mBase + r) * K + kt + sgrp);
            *(bf16x8*)(&Bs[r * LDSS + sgrp]) =
                load8(B + (size_t)(nBase + r) * K + kt + sgrp);
        }
        __syncthreads();

        bf16x8 afr[4], bfr[4];
        #pragma unroll
        for (int i = 0; i < 4; ++i)
            afr[i] = *(const bf16x8*)(&As[(wm + 16 * i + m16) * LDSS + quad * 8]);
        #pragma unroll
        for (int j = 0; j < 4; ++j)
            bfr[j] = *(const bf16x8*)(&Bs[(wn + 16 * j + m16) * LDSS + quad * 8]);
        #pragma unroll
        for (int i = 0; i < 4; ++i)
            #pragma unroll
            for (int j = 0; j < 4; ++j)
                acc[i][j] = __builtin_amdgcn_mfma_f32_16x16x32_bf16(
                    afr[i], bfr[j], acc[i][j], 0, 0, 0);
    }

    float bv[4];
    #pragma unroll
    for (int j = 0; j < 4; ++j)
        bv[j] = bias[nBase + wn + 16 * j + m16];

    #pragma unroll
    for (int i = 0; i < 4; ++i)
        #pragma unroll
        for (int j = 0; j < 4; ++j) {
            int col = nBase + wn + 16 * j + m16;
            #pragma unroll
            for (int r = 0; r < 4; ++r) {
                int row = mBase + wm + 16 * i + quad * 4 + r;
                store_out(&C[(size_t)row * N + col], acc[i][j][r] + bv[j]);
            }
        }
}

// ---------------------------------------------------------------------------
// RoPE in-place on q (heads 0..23) and k (cols 3072..3327), 8 elems/thread
// ---------------------------------------------------------------------------
__global__ void rope_kernel(__hip_bfloat16* __restrict__ qkv,
                            const float* __restrict__ cosb,
                            const float* __restrict__ sinb, int T)
{
    int idx = blockIdx.x * 256 + threadIdx.x;          // (t, h, j): j = d/8
    int total = T * 26 * 8;
    if (idx >= total) return;
    int j = idx & 7;
    int h = (idx >> 3) % 26;
    int t = idx / (26 * 8);
    int col = (h < 24) ? h * 128 : 3072 + (h - 24) * 128;
    int d0 = j * 8;
    size_t base = (size_t)t * 3584 + col + d0;
    bf16x8 x1 = *(const bf16x8*)((const short*)qkv + base);
    bf16x8 x2 = *(const bf16x8*)((const short*)qkv + base + 64);
    float4 c0 = *(const float4*)(cosb + t * 64 + d0);
    float4 c1 = *(const float4*)(cosb + t * 64 + d0 + 4);
    float4 s0 = *(const float4*)(sinb + t * 64 + d0);
    float4 s1 = *(const float4*)(sinb + t * 64 + d0 + 4);
    float cc[8] = {c0.x, c0.y, c0.z, c0.w, c1.x, c1.y, c1.z, c1.w};
    float ss[8] = {s0.x, s0.y, s0.z, s0.w, s1.x, s1.y, s1.z, s1.w};
    bf16x8 o1, o2;
    #pragma unroll
    for (int i = 0; i < 8; ++i) {
        float f1 = bf_bits2f(x1[i]);
        float f2 = bf_bits2f(x2[i]);
        o1[i] = f2bf_bits(f1 * cc[i] - f2 * ss[i]);
        o2[i] = f2bf_bits(f2 * cc[i] + f1 * ss[i]);
    }
    *(bf16x8*)((short*)qkv + base)      = o1;
    *(bf16x8*)((short*)qkv + base + 64) = o2;
}

// ---------------------------------------------------------------------------
// Flash attention v7 = v6 + K-tile preload: both K (8x b128 -> kreg) and V
// (2x b128) are issued BEFORE B1, so their L2/HBM latency hides under the
// barrier wait + V-transpose + lgkm drain + B2 window. QK is then pure
// register MFMA. Single Vt buffer, QBLK=128, LPT remap — all unchanged.
// ---------------------------------------------------------------------------
#define SM_SHIFT 12.0f

__global__ __launch_bounds__(256, 3) void attn_kernel(
    const __hip_bfloat16* __restrict__ qkv,  // T x 3584 (rope applied)
    __hip_bfloat16* __restrict__ out,        // T x 3072
    const int* __restrict__ seq_len_p, const int* __restrict__ window_p)
{
    const int S = seq_len_p[0];
    const int window = window_p[0];
    const float scale = 0.088388347648318447f;  // 1/sqrt(128)

    const int h   = blockIdx.y;
    const int kvh = h / 12;
    const int tid  = threadIdx.x;
    const int lane = tid & 63;
    const int wid  = tid >> 6;
    const int quad = lane >> 4;
    const int m16  = lane & 15;

    // heavy-first remap: descending qb within each batch (LPT scheduling)
    const int nbb = S >> 7;                  // q-blocks (128 rows) per batch
    const int b   = blockIdx.x / nbb;
    const int ib  = blockIdx.x - b * nbb;
    const int qb  = (nbb - 1 - ib) << 7;
    const int qb_global = b * S + qb;

    __shared__ short Vt[128 * 72];      // V^T: V[key][d] at [d*72 + key + ((d>>3)&1)*32]
    __shared__ short Ps[4][32 * 40];    // per-wave P [q][key], stride 40

    const size_t kvrow0 = (size_t)(b * S) * 3584 + 3072 + kvh * 128;

    bf16x8 qf[2][4];
    {
        const __hip_bfloat16* qp =
            qkv + (size_t)(qb_global + wid * 32 + m16) * 3584 + h * 128;
        #pragma unroll
        for (int qt = 0; qt < 2; ++qt)
            #pragma unroll
            for (int dc = 0; dc < 4; ++dc)
                qf[qt][dc] = *(const bf16x8*)(qp + qt * 16 * 3584 + dc * 32 + quad * 8);
    }

    f32x4 accO[2][8] = {};
    float lqt[2] = {0.f, 0.f};

    int ka0 = qb - window + 1;
    if (ka0 < 0) ka0 = 0;
    ka0 &= ~31;
    const int kend = qb + 128;
    const int niter = (kend - ka0) >> 5;

    // staging geometry (per thread): 2 chunks, each = one V row-slice of 8
    const int skey = tid & 31;          // key within 32-tile
    const int sgg0 = tid >> 5;          // 0..7  (chunk 0 d-group)
    const int sgg1 = sgg0 + 8;          // 8..15 (chunk 1 d-group)

    for (int it = 0; it < niter; ++it) {
        const int kt = ka0 + it * 32;

        // issue V loads first, then K-tile loads -- all fly across B1; the
        // V-transpose's vmcnt wait only needs v0/v1, K can keep flying.
        bf16x8 v0 = *(const bf16x8*)(qkv + kvrow0 + (size_t)(kt + skey) * 3584 + 256 + sgg0 * 8);
        bf16x8 v1 = *(const bf16x8*)(qkv + kvrow0 + (size_t)(kt + skey) * 3584 + 256 + sgg1 * 8);
        bf16x8 kreg[2][4];
        {
            const __hip_bfloat16* kp =
                qkv + kvrow0 + (size_t)(kt + m16) * 3584 + quad * 8;
            #pragma unroll
            for (int st = 0; st < 2; ++st)
                #pragma unroll
                for (int dc = 0; dc < 4; ++dc)
                    kreg[st][dc] = *(const bf16x8*)(kp + (size_t)st * 16 * 3584 + dc * 32);
        }
        __builtin_amdgcn_sched_barrier(0);   // pin load issue before B1

        // B1: all waves' previous-iter PV reads of Vt are complete (data-dep
        // ordered before this barrier); raw barrier keeps loads in flight
        __builtin_amdgcn_s_barrier();

        // transpose-write V^T (compiler inserts vmcnt wait for v0/v1)
        {
            short* dst0 = &Vt[(sgg0 * 8) * 72 + skey + (sgg0 & 1) * 32];
            short* dst1 = &Vt[(sgg1 * 8) * 72 + skey + (sgg1 & 1) * 32];
            #pragma unroll
            for (int i2 = 0; i2 < 8; ++i2) dst0[i2 * 72] = v0[i2];
            #pragma unroll
            for (int i2 = 0; i2 < 8; ++i2) dst1[i2 * 72] = v1[i2];
        }
        asm volatile("s_waitcnt lgkmcnt(0)" ::: "memory");
        // B2: Vt ready for all waves
        __builtin_amdgcn_s_barrier();
        __builtin_amdgcn_sched_barrier(0);

        // S^T = K * Q^T -- pure register MFMA (K preloaded)
        f32x4 sacc[2][2] = {};   // [st][qt]
        __builtin_amdgcn_s_setprio(1);
        #pragma unroll
        for (int st = 0; st < 2; ++st)
            #pragma unroll
            for (int dc = 0; dc < 4; ++dc) {
                sacc[st][0] = __builtin_amdgcn_mfma_f32_16x16x32_bf16(
                    kreg[st][dc], qf[0][dc], sacc[st][0], 0, 0, 0);
                sacc[st][1] = __builtin_amdgcn_mfma_f32_16x16x32_bf16(
                    kreg[st][dc], qf[1][dc], sacc[st][1], 0, 0, 0);
            }
        __builtin_amdgcn_s_setprio(0);

        // fixed-shift softmax: p = exp(s*scale - SHIFT); no rescaling ever.
        // S^T C-layout: col m16 = q, row quad*4 + r + st*16 = key
        #pragma unroll
        for (int qt = 0; qt < 2; ++qt) {
            const int qmin = qb + wid * 32 + qt * 16;     // wave-uniform
            short* prow = &Ps[wid][(qt * 16 + m16) * 40];
            float psum = 0.f;
            if (kt <= qmin - 31 && kt >= qmin + 16 - window) {
                // interior: all 32 keys valid for all 16 q
                #pragma unroll
                for (int st = 0; st < 2; ++st)
                    #pragma unroll
                    for (int r = 0; r < 4; ++r) {
                        float pp = __expf(fminf(
                            sacc[st][qt][r] * scale - SM_SHIFT, 80.f));
                        psum += pp;
                        prow[st * 16 + quad * 4 + r] = f2bf_bits(pp);
                    }
            } else {
                const int dl_base = (qmin + m16) - (kt + quad * 4);
                #pragma unroll
                for (int st = 0; st < 2; ++st)
                    #pragma unroll
                    for (int r = 0; r < 4; ++r) {
                        int dl = dl_base - st * 16 - r;
                        float pp = ((unsigned)dl < (unsigned)window)
                            ? __expf(fminf(sacc[st][qt][r] * scale - SM_SHIFT, 80.f))
                            : 0.f;
                        psum += pp;
                        prow[st * 16 + quad * 4 + r] = f2bf_bits(pp);
                    }
            }
            psum += __shfl_xor(psum, 16, 64);
            psum += __shfl_xor(psum, 32, 64);
            lqt[qt] += psum;
        }

        // PV: A = P (wave-private LDS), B = V^T frag
        bf16x8 pf0 = *(const bf16x8*)(&Ps[wid][(0  + m16) * 40 + quad * 8]);
        bf16x8 pf1 = *(const bf16x8*)(&Ps[wid][(16 + m16) * 40 + quad * 8]);
        __builtin_amdgcn_s_setprio(1);
        #pragma unroll
        for (int dt = 0; dt < 8; ++dt) {
            int row = dt * 16 + m16;
            bf16x8 vf = *(const bf16x8*)(&Vt[row * 72 + quad * 8 + ((row >> 3) & 1) * 32]);
            accO[0][dt] = __builtin_amdgcn_mfma_f32_16x16x32_bf16(pf0, vf, accO[0][dt], 0, 0, 0);
            accO[1][dt] = __builtin_amdgcn_mfma_f32_16x16x32_bf16(pf1, vf, accO[1][dt], 0, 0, 0);
        }
        __builtin_amdgcn_s_setprio(0);
    }

    // epilogue: O /= l
    #pragma unroll
    for (int qt = 0; qt < 2; ++qt) {
        float li[4];
        #pragma unroll
        for (int r = 0; r < 4; ++r)
            li[r] = 1.0f / __shfl(lqt[qt], quad * 4 + r, 64);
        #pragma unroll
        for (int r = 0; r < 4; ++r) {
            int t = qb_global + wid * 32 + qt * 16 + quad * 4 + r;
            __hip_bfloat16* op = out + (size_t)t * 3072 + h * 128 + m16;
            #pragma unroll
            for (int dt = 0; dt < 8; ++dt)
                op[dt * 16] = __float2bfloat16(accO[qt][dt][r] * li[r]);
        }
    }
}

// ---------------------------------------------------------------------------
extern "C" void kernel_launch(void* const* d_in, const int* in_sizes, int n_in,
                              void* d_out, int out_size, void* d_ws, size_t ws_size,
                              hipStream_t stream) {
    const float* hidden = (const float*)d_in[0];
    const float* w_qkv  = (const float*)d_in[1];
    const float* b_qkv  = (const float*)d_in[2];
    const float* w_o    = (const float*)d_in[3];
    const float* b_o    = (const float*)d_in[4];
    const float* cosb   = (const float*)d_in[5];
    const float* sinb   = (const float*)d_in[6];
    const int* seq_len_p = (const int*)d_in[7];
    const int* window_p  = (const int*)d_in[8];

    const int HID  = in_sizes[4];            // 3072
    const int NQKV = in_sizes[2];            // 3584
    const int T    = in_sizes[0] / HID;      // 4096

    size_t off = 0;
    auto alloc = [&](size_t bytes) {
        char* p = (char*)d_ws + off;
        off = (off + bytes + 255) & ~(size_t)255;
        return p;
    };
    __hip_bfloat16* qkv      = (__hip_bfloat16*)alloc((size_t)T * NQKV * 2);
    __hip_bfloat16* attn_out = (__hip_bfloat16*)alloc((size_t)T * HID * 2);
    __hip_bfloat16* hid_bf = (__hip_bfloat16*)alloc((size_t)T * HID * 2);
    __hip_bfloat16* wq_bf  = (__hip_bfloat16*)alloc((size_t)NQKV * HID * 2);
    __hip_bfloat16* wo_bf  = (__hip_bfloat16*)alloc((size_t)HID * HID * 2);
    const bool pre = (ws_size >= off);
    const bool big = pre && (T % 256 == 0) && (NQKV % 256 == 0) &&
                     (HID % 256 == 0) && (HID % 64 == 0);

    dim3 blk(256);

    if (big) {
        int n8h = T * HID / 8, n8q = NQKV * HID / 8, n8o = HID * HID / 8;
        int n8 = n8h + n8q + n8o;
        cvt3_f32_bf16<<<dim3((n8 + 255) / 256), blk, 0, stream>>>(
            hidden, (short*)hid_bf, n8h, w_qkv, (short*)wq_bf, n8q,
            w_o, (short*)wo_bf, n8o);
        gemm256<__hip_bfloat16><<<dim3(NQKV / 256, T / 256), dim3(512), 0, stream>>>(
            hid_bf, wq_bf, b_qkv, qkv, T, NQKV, HID);
    } else {
        gemm_bt_bias<float, float, __hip_bfloat16>
            <<<dim3(NQKV / 128, T / 128), blk, 0, stream>>>(
            hidden, w_qkv, b_qkv, qkv, T, NQKV, HID);
    }

    int total = T * 26 * 8;
    rope_kernel<<<dim3((total + 255) / 256), blk, 0, stream>>>(qkv, cosb, sinb, T);

    attn_kernel<<<dim3(T / 128, 24), blk, 0, stream>>>(qkv, attn_out, seq_len_p, window_p);

    if (big) {
        gemm256<float><<<dim3(HID / 256, T / 256), dim3(512), 0, stream>>>(
            attn_out, wo_bf, b_o, (float*)d_out, T, HID, HID);
    } else {
        gemm_bt_bias<__hip_bfloat16, float, float>
            <<<dim3(HID / 128, T / 128), blk, 0, stream>>>(
            attn_out, w_o, b_o, (float*)d_out, T, HID, HID);
    }
}

// Round 6
// 470.549 us; speedup vs baseline: 1.3687x; 1.0146x over previous
//
#include <hip/hip_runtime.h>
#include <hip/hip_bf16.h>

typedef __attribute__((ext_vector_type(8))) short bf16x8;
typedef __attribute__((ext_vector_type(4))) float f32x4;

__device__ __forceinline__ short f2bf_bits(float f) {
    __hip_bfloat16 h = __float2bfloat16(f);
    short s;
    __builtin_memcpy(&s, &h, 2);
    return s;
}

__device__ __forceinline__ float bf_bits2f(short s) {
    unsigned int u = ((unsigned int)(unsigned short)s) << 16;
    float f;
    __builtin_memcpy(&f, &u, 4);
    return f;
}

__device__ __forceinline__ bf16x8 load8(const float* p) {
    float4 a = *(const float4*)p;
    float4 b = *(const float4*)(p + 4);
    bf16x8 r;
    r[0] = f2bf_bits(a.x); r[1] = f2bf_bits(a.y);
    r[2] = f2bf_bits(a.z); r[3] = f2bf_bits(a.w);
    r[4] = f2bf_bits(b.x); r[5] = f2bf_bits(b.y);
    r[6] = f2bf_bits(b.z); r[7] = f2bf_bits(b.w);
    return r;
}
__device__ __forceinline__ bf16x8 load8(const __hip_bfloat16* p) {
    return *(const bf16x8*)p;
}

__device__ __forceinline__ void store_out(__hip_bfloat16* p, float v) {
    *p = __float2bfloat16(v);
}
__device__ __forceinline__ void store_out(float* p, float v) { *p = v; }

// ---------------------------------------------------------------------------
// merged f32 -> bf16 bulk convert of three buffers (8 elems/thread)
// ---------------------------------------------------------------------------
__global__ void cvt3_f32_bf16(const float* __restrict__ a, short* __restrict__ da, int na8,
                              const float* __restrict__ b, short* __restrict__ db, int nb8,
                              const float* __restrict__ c, short* __restrict__ dc, int nc8) {
    int i = blockIdx.x * 256 + threadIdx.x;
    if (i < na8) {
        *(bf16x8*)(da + (size_t)i * 8) = load8(a + (size_t)i * 8);
    } else if ((i -= na8) < nb8) {
        *(bf16x8*)(db + (size_t)i * 8) = load8(b + (size_t)i * 8);
    } else if ((i -= nb8) < nc8) {
        *(bf16x8*)(dc + (size_t)i * 8) = load8(c + (size_t)i * 8);
    }
}

// ---------------------------------------------------------------------------
// 256x256 8-phase GEMM (bf16 x bf16): C = A(MxK) * B(NxK)^T + bias.
// ---------------------------------------------------------------------------
#define GB_REG 65536

__device__ __forceinline__ int half_off(int buf, int half) {
    return buf * 32768 + half * 16384;
}

template <typename TC>
__global__ __launch_bounds__(512) void gemm256(
    const __hip_bfloat16* __restrict__ A, const __hip_bfloat16* __restrict__ B,
    const float* __restrict__ bias, TC* __restrict__ C, int M, int N, int K)
{
    __shared__ char smem[131072];

    const int tid  = threadIdx.x;
    const int lane = tid & 63;
    const int wid  = tid >> 6;
    const int quad = lane >> 4;
    const int m16  = lane & 15;
    const int wmg  = wid >> 2;       // 0..1 -> A half (M 128-row group)
    const int wng  = wid & 3;        // 0..3 -> N 64-col group
    const int bhalf = wng >> 1;      // B half
    const int bsub  = (wng & 1) * 4; // subtile row base within B half

    // XCD-chunked block swizzle (bijective: nwg % 8 == 0 for our shapes)
    const int gx  = gridDim.x;
    const int nwg = gx * gridDim.y;
    int lin = blockIdx.y * gx + blockIdx.x;
    if ((nwg & 7) == 0) {
        int q = nwg >> 3;
        lin = (lin & 7) * q + (lin >> 3);
    }
    const int bn = lin % gx, bm = lin / gx;
    const int mBase = bm * 256, nBase = bn * 256;

    // swizzled ds_read offset within a subtile (v2 swizzle)
    const int roff = (m16 << 6) | ((quad * 16) ^ (((m16 >> 1) & 3) << 4));

    // staging: thread's linear LDS slot X = l*8192 + tid*16 -> source (r,c)
    int r_s[2], c_s[2];
    #pragma unroll
    for (int l = 0; l < 2; ++l) {
        int sub = l * 8 + wid;
        int r16 = (tid >> 2) & 15;
        int cb  = ((tid & 3) * 16) ^ (((r16 >> 1) & 3) << 4);
        r_s[l] = (sub >> 1) * 16 + r16;
        c_s[l] = (sub & 1) * 32 + (cb >> 1);
    }

    const __hip_bfloat16* Ab = A + (size_t)mBase * K;
    const __hip_bfloat16* Bb = B + (size_t)nBase * K;

    auto stage = [&](int region, const __hip_bfloat16* base, int buf, int half, int tile) {
        const __hip_bfloat16* gb = base + (size_t)(half * 128) * K + tile * 64;
        #pragma unroll
        for (int l = 0; l < 2; ++l) {
            const __hip_bfloat16* g = gb + (size_t)r_s[l] * K + c_s[l];
            short* lb = (short*)(smem + region + half_off(buf, half) + l * 8192 + wid * 1024);
            __builtin_amdgcn_global_load_lds(
                (__attribute__((address_space(1))) void*)g,
                (__attribute__((address_space(3))) void*)lb, 16, 0, 0);
        }
    };

    f32x4 acc[8][4] = {};
    bf16x8 afr[4][2];       // 4 m-frags x 2 k-slices (current m-quartet)
    bf16x8 bfr[2][2][2];    // [n-pair g][j][ks] -- both n-pairs stay live

    auto LD_A = [&](int buf, int g) {
        const char* base = smem + half_off(buf, wmg) + (g ? 8192 : 0);
        #pragma unroll
        for (int m = 0; m < 4; ++m)
            #pragma unroll
            for (int ks = 0; ks < 2; ++ks)
                afr[m][ks] = *(const bf16x8*)(base + ((m * 2 + ks) << 10) + roff);
    };
    auto LD_B = [&](int buf, int g) {
        const char* base = smem + GB_REG + half_off(buf, bhalf) + ((bsub + g * 2) << 11);
        #pragma unroll
        for (int j = 0; j < 2; ++j)
            #pragma unroll
            for (int ks = 0; ks < 2; ++ks)
                bfr[g][j][ks] = *(const bf16x8*)(base + ((j * 2 + ks) << 10) + roff);
    };
    auto MM = [&](int mo, int g) {
        #pragma unroll
        for (int m = 0; m < 4; ++m)
            #pragma unroll
            for (int j = 0; j < 2; ++j)
                #pragma unroll
                for (int ks = 0; ks < 2; ++ks)
                    acc[mo + m][g * 2 + j] = __builtin_amdgcn_mfma_f32_16x16x32_bf16(
                        afr[m][ks], bfr[g][j][ks], acc[mo + m][g * 2 + j], 0, 0, 0);
    };

#define SBAR() __builtin_amdgcn_s_barrier()
#define WAIT_LGKM0() do { asm volatile("s_waitcnt lgkmcnt(0)" ::: "memory"); \
                          __builtin_amdgcn_sched_barrier(0); } while (0)
#define WAIT_VM4()   do { asm volatile("s_waitcnt vmcnt(4)"   ::: "memory"); \
                          __builtin_amdgcn_sched_barrier(0); } while (0)

    const int NT = K >> 6;

    // prologue: tile0 -> buf0 (all 4 halves), tile1 -> buf1 (B.h0, A.h0)
    stage(GB_REG, Bb, 0, 0, 0);
    stage(0,      Ab, 0, 0, 0);
    stage(GB_REG, Bb, 0, 1, 0);
    stage(0,      Ab, 0, 1, 0);
    stage(GB_REG, Bb, 1, 0, 1);
    stage(0,      Ab, 1, 0, 1);
    WAIT_VM4();      // tile0's 8 loads done; tile1's 4 may fly
    SBAR();

    for (int i = 0; i < (NT >> 1); ++i) {
        const int to = 2 * i + 1;
        const int t2 = min(2 * i + 2, NT - 1);
        const int t3 = min(2 * i + 3, NT - 1);
        // P0: quadrant (m0-3, n0-1) of even tile (buf0)
        LD_A(0, 0); LD_B(0, 0);
        stage(GB_REG, Bb, 1, 1, to);
        SBAR(); WAIT_LGKM0();
        __builtin_amdgcn_s_setprio(1); MM(0, 0); __builtin_amdgcn_s_setprio(0);
        SBAR();
        // P1: (m0-3, n2-3)
        LD_B(0, 1);
        stage(0, Ab, 1, 1, to);
        SBAR(); WAIT_LGKM0();
        __builtin_amdgcn_s_setprio(1); MM(0, 1); __builtin_amdgcn_s_setprio(0);
        SBAR();
        // P2: (m4-7, n2-3)
        LD_A(0, 1);
        stage(GB_REG, Bb, 0, 0, t2);
        SBAR(); WAIT_LGKM0();
        __builtin_amdgcn_s_setprio(1); MM(4, 1); __builtin_amdgcn_s_setprio(0);
        SBAR();
        // P3: (m4-7, n0-1) register-only; gate odd-tile arrival (counted vmcnt)
        stage(0, Ab, 0, 0, t2);
        WAIT_VM4();
        SBAR();
        __builtin_amdgcn_s_setprio(1); MM(4, 0); __builtin_amdgcn_s_setprio(0);
        SBAR();
        // P4: odd tile (buf1), (m0-3, n0-1)
        LD_A(1, 0); LD_B(1, 0);
        stage(GB_REG, Bb, 0, 1, t2);
        SBAR(); WAIT_LGKM0();
        __builtin_amdgcn_s_setprio(1); MM(0, 0); __builtin_amdgcn_s_setprio(0);
        SBAR();
        // P5: (m0-3, n2-3)
        LD_B(1, 1);
        stage(0, Ab, 0, 1, t2);
        SBAR(); WAIT_LGKM0();
        __builtin_amdgcn_s_setprio(1); MM(0, 1); __builtin_amdgcn_s_setprio(0);
        SBAR();
        // P6: (m4-7, n2-3)
        LD_A(1, 1);
        stage(GB_REG, Bb, 1, 0, t3);
        SBAR(); WAIT_LGKM0();
        __builtin_amdgcn_s_setprio(1); MM(4, 1); __builtin_amdgcn_s_setprio(0);
        SBAR();
        // P7: (m4-7, n0-1) register-only; gate even-tile arrival
        stage(0, Ab, 1, 0, t3);
        WAIT_VM4();
        SBAR();
        __builtin_amdgcn_s_setprio(1); MM(4, 0); __builtin_amdgcn_s_setprio(0);
        SBAR();
    }

#undef SBAR
#undef WAIT_LGKM0
#undef WAIT_VM4

    float bv[4];
    #pragma unroll
    for (int j = 0; j < 4; ++j)
        bv[j] = bias[nBase + wng * 64 + j * 16 + m16];

    #pragma unroll
    for (int mf = 0; mf < 8; ++mf) {
        #pragma unroll
        for (int j = 0; j < 4; ++j) {
            const int col = nBase + wng * 64 + j * 16 + m16;
            #pragma unroll
            for (int r = 0; r < 4; ++r) {
                const int row = mBase + wmg * 128 + mf * 16 + quad * 4 + r;
                store_out(&C[(size_t)row * N + col], acc[mf][j][r] + bv[j]);
            }
        }
    }
}

// ---------------------------------------------------------------------------
// Fallback GEMM (fp32 inputs converted inline) — safety net if ws too small
// ---------------------------------------------------------------------------
#define LDSS 40

template <typename TA, typename TB, typename TC>
__global__ __launch_bounds__(256) void gemm_bt_bias(
    const TA* __restrict__ A, const TB* __restrict__ B,
    const float* __restrict__ bias, TC* __restrict__ C, int M, int N, int K)
{
    __shared__ short As[128 * LDSS];
    __shared__ short Bs[128 * LDSS];

    const int tid  = threadIdx.x;
    const int lane = tid & 63;
    const int wid  = tid >> 6;
    const int quad = lane >> 4;
    const int m16  = lane & 15;

    const int mBase = blockIdx.y * 128;
    const int nBase = blockIdx.x * 128;
    const int wm = (wid >> 1) * 64;
    const int wn = (wid & 1) * 64;

    f32x4 acc[4][4] = {};
    const int srow = tid >> 2;
    const int sgrp = (tid & 3) * 8;

    for (int kt = 0; kt < K; kt += 32) {
        __syncthreads();
        for (int p = 0; p < 2; ++p) {
            int r = srow + p * 64;
            *(bf16x8*)(&As[r * LDSS + sgrp]) =
                load8(A + (size_t)(mBase + r) * K + kt + sgrp);
            *(bf16x8*)(&Bs[r * LDSS + sgrp]) =
                load8(B + (size_t)(nBase + r) * K + kt + sgrp);
        }
        __syncthreads();

        bf16x8 afr[4], bfr[4];
        #pragma unroll
        for (int i = 0; i < 4; ++i)
            afr[i] = *(const bf16x8*)(&As[(wm + 16 * i + m16) * LDSS + quad * 8]);
        #pragma unroll
        for (int j = 0; j < 4; ++j)
            bfr[j] = *(const bf16x8*)(&Bs[(wn + 16 * j + m16) * LDSS + quad * 8]);
        #pragma unroll
        for (int i = 0; i < 4; ++i)
            #pragma unroll
            for (int j = 0; j < 4; ++j)
                acc[i][j] = __builtin_amdgcn_mfma_f32_16x16x32_bf16(
                    afr[i], bfr[j], acc[i][j], 0, 0, 0);
    }

    float bv[4];
    #pragma unroll
    for (int j = 0; j < 4; ++j)
        bv[j] = bias[nBase + wn + 16 * j + m16];

    #pragma unroll
    for (int i = 0; i < 4; ++i)
        #pragma unroll
        for (int j = 0; j < 4; ++j) {
            int col = nBase + wn + 16 * j + m16;
            #pragma unroll
            for (int r = 0; r < 4; ++r) {
                int row = mBase + wm + 16 * i + quad * 4 + r;
                store_out(&C[(size_t)row * N + col], acc[i][j][r] + bv[j]);
            }
        }
}

// ---------------------------------------------------------------------------
// RoPE in-place on q (heads 0..23) and k (cols 3072..3327), 8 elems/thread
// ---------------------------------------------------------------------------
__global__ void rope_kernel(__hip_bfloat16* __restrict__ qkv,
                            const float* __restrict__ cosb,
                            const float* __restrict__ sinb, int T)
{
    int idx = blockIdx.x * 256 + threadIdx.x;          // (t, h, j): j = d/8
    int total = T * 26 * 8;
    if (idx >= total) return;
    int j = idx & 7;
    int h = (idx >> 3) % 26;
    int t = idx / (26 * 8);
    int col = (h < 24) ? h * 128 : 3072 + (h - 24) * 128;
    int d0 = j * 8;
    size_t base = (size_t)t * 3584 + col + d0;
    bf16x8 x1 = *(const bf16x8*)((const short*)qkv + base);
    bf16x8 x2 = *(const bf16x8*)((const short*)qkv + base + 64);
    float4 c0 = *(const float4*)(cosb + t * 64 + d0);
    float4 c1 = *(const float4*)(cosb + t * 64 + d0 + 4);
    float4 s0 = *(const float4*)(sinb + t * 64 + d0);
    float4 s1 = *(const float4*)(sinb + t * 64 + d0 + 4);
    float cc[8] = {c0.x, c0.y, c0.z, c0.w, c1.x, c1.y, c1.z, c1.w};
    float ss[8] = {s0.x, s0.y, s0.z, s0.w, s1.x, s1.y, s1.z, s1.w};
    bf16x8 o1, o2;
    #pragma unroll
    for (int i = 0; i < 8; ++i) {
        float f1 = bf_bits2f(x1[i]);
        float f2 = bf_bits2f(x2[i]);
        o1[i] = f2bf_bits(f1 * cc[i] - f2 * ss[i]);
        o2[i] = f2bf_bits(f2 * cc[i] + f1 * ss[i]);
    }
    *(bf16x8*)((short*)qkv + base)      = o1;
    *(bf16x8*)((short*)qkv + base + 64) = o2;
}

// ---------------------------------------------------------------------------
// Flash attention v8: KVBLK=64 (half the barriers), P entirely in registers
// via phi-permuted K rows (QK C-layout == PV A-layout, zero shuffles/LDS),
// conflict-free packed-b32 V^T staging into two 32-key planes.
//   phi_st(m) = (m>>2)*8 + st*4 + (m&3)  -> C slot (st,quad,r) holds key
//   quad*8 + st*4 + r, which is exactly the 16x16x32 A-fragment order.
// Vt plane layout: V[key][d] at plane(key>>5)[ d*72 + (key&31) + ((d>>3)&1)*32 ]
// plane stride 9248 shorts (pad 32 -> +16 banks, write-conflict-free).
// ---------------------------------------------------------------------------
#define SM_SHIFT 12.0f
#define VPLANE 9248

__global__ __launch_bounds__(256, 3) void attn_kernel(
    const __hip_bfloat16* __restrict__ qkv,  // T x 3584 (rope applied)
    __hip_bfloat16* __restrict__ out,        // T x 3072
    const int* __restrict__ seq_len_p, const int* __restrict__ window_p)
{
    const int S = seq_len_p[0];
    const int window = window_p[0];
    const float scale = 0.088388347648318447f;  // 1/sqrt(128)

    const int h   = blockIdx.y;
    const int kvh = h / 12;
    const int tid  = threadIdx.x;
    const int lane = tid & 63;
    const int wid  = tid >> 6;
    const int quad = lane >> 4;
    const int m16  = lane & 15;

    // heavy-first remap: descending qb within each batch (LPT scheduling)
    const int nbb = S >> 7;                  // q-blocks (128 rows) per batch
    const int b   = blockIdx.x / nbb;
    const int ib  = blockIdx.x - b * nbb;
    const int qb  = (nbb - 1 - ib) << 7;
    const int qb_global = b * S + qb;

    __shared__ short Vt[2 * VPLANE];    // two 32-key planes of V^T

    const size_t kvrow0 = (size_t)(b * S) * 3584 + 3072 + kvh * 128;

    bf16x8 qf[2][4];
    {
        const __hip_bfloat16* qp =
            qkv + (size_t)(qb_global + wid * 32 + m16) * 3584 + h * 128;
        #pragma unroll
        for (int qt = 0; qt < 2; ++qt)
            #pragma unroll
            for (int dc = 0; dc < 4; ++dc)
                qf[qt][dc] = *(const bf16x8*)(qp + qt * 16 * 3584 + dc * 32 + quad * 8);
    }

    f32x4 accO[2][8] = {};
    float lqt[2] = {0.f, 0.f};

    int ka0 = qb - window + 1;
    if (ka0 < 0) ka0 = 0;
    ka0 &= ~63;
    const int kend = qb + 128;
    const int niter = (kend - ka0) >> 6;

    // V staging geometry: thread handles key pair (2j, 2j+1), d-chunks gg0, gg0+8
    const int jkey = tid & 31;          // key-pair index 0..31
    const int gg0  = tid >> 5;          // 0..7
    // phi-permuted K row offset (st added in loop)
    const int phi_base = ((m16 >> 2) << 3) + (m16 & 3);

    for (int it = 0; it < niter; ++it) {
        const int kt = ka0 + it * 64;

        // issue 4 V b128 loads BEFORE B1 (fly across the barrier)
        const __hip_bfloat16* vp =
            qkv + kvrow0 + (size_t)(kt + 2 * jkey) * 3584 + 256;
        bf16x8 va0 = *(const bf16x8*)(vp + gg0 * 8);
        bf16x8 vb0 = *(const bf16x8*)(vp + 3584 + gg0 * 8);
        bf16x8 va1 = *(const bf16x8*)(vp + (gg0 + 8) * 8);
        bf16x8 vb1 = *(const bf16x8*)(vp + 3584 + (gg0 + 8) * 8);
        __builtin_amdgcn_sched_barrier(0);

        // B1: previous iter's PV reads of Vt are complete
        __builtin_amdgcn_s_barrier();

        // packed-b32 transpose-write into planes (conflict-free)
        {
            short* pl = &Vt[(jkey >> 4) * VPLANE];
            const int colsh = 2 * (jkey & 15);
            #pragma unroll
            for (int i2 = 0; i2 < 8; ++i2) {
                unsigned dw0 = (unsigned)(unsigned short)va0[i2] |
                               ((unsigned)(unsigned short)vb0[i2] << 16);
                *(unsigned*)(pl + (gg0 * 8 + i2) * 72 + colsh + (gg0 & 1) * 32) = dw0;
            }
            #pragma unroll
            for (int i2 = 0; i2 < 8; ++i2) {
                unsigned dw1 = (unsigned)(unsigned short)va1[i2] |
                               ((unsigned)(unsigned short)vb1[i2] << 16);
                *(unsigned*)(pl + ((gg0 + 8) * 8 + i2) * 72 + colsh + ((gg0 + 8) & 1) * 32) = dw1;
            }
        }
        asm volatile("s_waitcnt lgkmcnt(0)" ::: "memory");
        // B2: Vt ready for all waves
        __builtin_amdgcn_s_barrier();
        __builtin_amdgcn_sched_barrier(0);

        bf16x8 pf[2][2];    // [qt][kb] PV A-fragments, built lane-locally

        #pragma unroll
        for (int kb = 0; kb < 2; ++kb) {
            const int ktb = kt + kb * 32;
            // QK with phi-permuted K rows
            f32x4 sacc[2][2] = {};   // [st][qt]
            #pragma unroll
            for (int st = 0; st < 2; ++st) {
                const __hip_bfloat16* kp =
                    qkv + kvrow0 + (size_t)(ktb + phi_base + st * 4) * 3584 + quad * 8;
                #pragma unroll
                for (int dc = 0; dc < 4; ++dc) {
                    bf16x8 kf = *(const bf16x8*)(kp + dc * 32);
                    sacc[st][0] = __builtin_amdgcn_mfma_f32_16x16x32_bf16(
                        kf, qf[0][dc], sacc[st][0], 0, 0, 0);
                    sacc[st][1] = __builtin_amdgcn_mfma_f32_16x16x32_bf16(
                        kf, qf[1][dc], sacc[st][1], 0, 0, 0);
                }
            }

            // softmax: slot (st,quad,r) holds key ktb + quad*8 + st*4 + r
            #pragma unroll
            for (int qt = 0; qt < 2; ++qt) {
                const int qmin = qb + wid * 32 + qt * 16;    // wave-uniform
                bf16x8 pfv;
                float psum = 0.f;
                if (ktb <= qmin - 31 && ktb >= qmin + 16 - window) {
                    #pragma unroll
                    for (int st = 0; st < 2; ++st)
                        #pragma unroll
                        for (int r = 0; r < 4; ++r) {
                            float pp = __expf(fminf(
                                sacc[st][qt][r] * scale - SM_SHIFT, 80.f));
                            psum += pp;
                            pfv[st * 4 + r] = f2bf_bits(pp);
                        }
                } else {
                    const int dl_base = (qmin + m16) - (ktb + quad * 8);
                    #pragma unroll
                    for (int st = 0; st < 2; ++st)
                        #pragma unroll
                        for (int r = 0; r < 4; ++r) {
                            int dl = dl_base - st * 4 - r;
                            float pp = ((unsigned)dl < (unsigned)window)
                                ? __expf(fminf(sacc[st][qt][r] * scale - SM_SHIFT, 80.f))
                                : 0.f;
                            psum += pp;
                            pfv[st * 4 + r] = f2bf_bits(pp);
                        }
                }
                psum += __shfl_xor(psum, 16, 64);
                psum += __shfl_xor(psum, 32, 64);
                lqt[qt] += psum;
                pf[qt][kb] = pfv;
            }
        }

        // PV: A = pf (registers), B = V^T fragment from plane kb
        __builtin_amdgcn_s_setprio(1);
        #pragma unroll
        for (int kb = 0; kb < 2; ++kb) {
            const short* pl = &Vt[kb * VPLANE];
            #pragma unroll
            for (int dt = 0; dt < 8; ++dt) {
                int row = dt * 16 + m16;
                bf16x8 vf = *(const bf16x8*)(pl + row * 72 + quad * 8 + ((row >> 3) & 1) * 32);
                accO[0][dt] = __builtin_amdgcn_mfma_f32_16x16x32_bf16(
                    pf[0][kb], vf, accO[0][dt], 0, 0, 0);
                accO[1][dt] = __builtin_amdgcn_mfma_f32_16x16x32_bf16(
                    pf[1][kb], vf, accO[1][dt], 0, 0, 0);
            }
        }
        __builtin_amdgcn_s_setprio(0);
    }

    // epilogue: O /= l
    #pragma unroll
    for (int qt = 0; qt < 2; ++qt) {
        float li[4];
        #pragma unroll
        for (int r = 0; r < 4; ++r)
            li[r] = 1.0f / __shfl(lqt[qt], quad * 4 + r, 64);
        #pragma unroll
        for (int r = 0; r < 4; ++r) {
            int t = qb_global + wid * 32 + qt * 16 + quad * 4 + r;
            __hip_bfloat16* op = out + (size_t)t * 3072 + h * 128 + m16;
            #pragma unroll
            for (int dt = 0; dt < 8; ++dt)
                op[dt * 16] = __float2bfloat16(accO[qt][dt][r] * li[r]);
        }
    }
}

// ---------------------------------------------------------------------------
extern "C" void kernel_launch(void* const* d_in, const int* in_sizes, int n_in,
                              void* d_out, int out_size, void* d_ws, size_t ws_size,
                              hipStream_t stream) {
    const float* hidden = (const float*)d_in[0];
    const float* w_qkv  = (const float*)d_in[1];
    const float* b_qkv  = (const float*)d_in[2];
    const float* w_o    = (const float*)d_in[3];
    const float* b_o    = (const float*)d_in[4];
    const float* cosb   = (const float*)d_in[5];
    const float* sinb   = (const float*)d_in[6];
    const int* seq_len_p = (const int*)d_in[7];
    const int* window_p  = (const int*)d_in[8];

    const int HID  = in_sizes[4];            // 3072
    const int NQKV = in_sizes[2];            // 3584
    const int T    = in_sizes[0] / HID;      // 4096

    size_t off = 0;
    auto alloc = [&](size_t bytes) {
        char* p = (char*)d_ws + off;
        off = (off + bytes + 255) & ~(size_t)255;
        return p;
    };
    __hip_bfloat16* qkv      = (__hip_bfloat16*)alloc((size_t)T * NQKV * 2);
    __hip_bfloat16* attn_out = (__hip_bfloat16*)alloc((size_t)T * HID * 2);
    __hip_bfloat16* hid_bf = (__hip_bfloat16*)alloc((size_t)T * HID * 2);
    __hip_bfloat16* wq_bf  = (__hip_bfloat16*)alloc((size_t)NQKV * HID * 2);
    __hip_bfloat16* wo_bf  = (__hip_bfloat16*)alloc((size_t)HID * HID * 2);
    const bool pre = (ws_size >= off);
    const bool big = pre && (T % 256 == 0) && (NQKV % 256 == 0) &&
                     (HID % 256 == 0) && (HID % 64 == 0);

    dim3 blk(256);

    if (big) {
        int n8h = T * HID / 8, n8q = NQKV * HID / 8, n8o = HID * HID / 8;
        int n8 = n8h + n8q + n8o;
        cvt3_f32_bf16<<<dim3((n8 + 255) / 256), blk, 0, stream>>>(
            hidden, (short*)hid_bf, n8h, w_qkv, (short*)wq_bf, n8q,
            w_o, (short*)wo_bf, n8o);
        gemm256<__hip_bfloat16><<<dim3(NQKV / 256, T / 256), dim3(512), 0, stream>>>(
            hid_bf, wq_bf, b_qkv, qkv, T, NQKV, HID);
    } else {
        gemm_bt_bias<float, float, __hip_bfloat16>
            <<<dim3(NQKV / 128, T / 128), blk, 0, stream>>>(
            hidden, w_qkv, b_qkv, qkv, T, NQKV, HID);
    }

    int total = T * 26 * 8;
    rope_kernel<<<dim3((total + 255) / 256), blk, 0, stream>>>(qkv, cosb, sinb, T);

    attn_kernel<<<dim3(T / 128, 24), blk, 0, stream>>>(qkv, attn_out, seq_len_p, window_p);

    if (big) {
        gemm256<float><<<dim3(HID / 256, T / 256), dim3(512), 0, stream>>>(
            attn_out, wo_bf, b_o, (float*)d_out, T, HID, HID);
    } else {
        gemm_bt_bias<__hip_bfloat16, float, float>
            <<<dim3(HID / 128, T / 128), blk, 0, stream>>>(
            attn_out, w_o, b_o, (float*)d_out, T, HID, HID);
    }
}